// Round 1
// baseline (645.760 us; speedup 1.0000x reference)
//
#include <hip/hip_runtime.h>

typedef unsigned short u16;
typedef unsigned int   u32;
typedef __attribute__((ext_vector_type(4))) float  fvec4;
typedef __attribute__((ext_vector_type(8))) __bf16 bvec8;

#define NB    64
#define SEQL  512
#define DCH   321
#define BDTOT (NB * DCH)      /* 20544 */
#define NWIN  17
#define PREDL 96

__device__ __forceinline__ u16 f2bf(float f) {
    union { float f; u32 u; } v; v.f = f;
    u32 r = v.u + 0x7FFFu + ((v.u >> 16) & 1u);
    return (u16)(r >> 16);
}
__device__ __forceinline__ float lrelu(float v) { return v > 0.f ? v : 0.01f * v; }

__device__ __forceinline__ void gld16(const u16* g, u16* l) {
    __builtin_amdgcn_global_load_lds((const __attribute__((address_space(1))) void*)g,
                                     (__attribute__((address_space(3))) void*)l, 16, 0, 0);
}

// ---------------- stats: mean / rstd / std per (b,d) over SEQ ----------------
__global__ __launch_bounds__(256) void stats_kernel(const float* __restrict__ x,
                                                    float* __restrict__ mean,
                                                    float* __restrict__ rstd,
                                                    float* __restrict__ stdv) {
    __shared__ float ls[2][4][64];
    int i = threadIdx.x & 63;
    int j = threadIdx.x >> 6;
    int bd = blockIdx.x * 64 + i;
    int b = bd / DCH, d = bd - b * DCH;
    float s = 0.f, ss = 0.f;
    for (int t = j; t < SEQL; t += 4) {
        float v = x[((size_t)b * SEQL + t) * DCH + d];
        s += v; ss += v * v;
    }
    ls[0][j][i] = s; ls[1][j][i] = ss;
    __syncthreads();
    if (j == 0) {
        s  = ls[0][0][i] + ls[0][1][i] + ls[0][2][i] + ls[0][3][i];
        ss = ls[1][0][i] + ls[1][1][i] + ls[1][2][i] + ls[1][3][i];
        float m   = s * (1.f / SEQL);
        float var = ss * (1.f / SEQL) - m * m;
        float st  = sqrtf(var + 1e-5f);
        mean[bd] = m; rstd[bd] = 1.f / st; stdv[bd] = st;
    }
}

// -------- normalize + transpose: x(B,SEQ,D) -> xnT(B*D, 576) bf16, +32 pad --------
__global__ __launch_bounds__(256) void norm_transpose(const float* __restrict__ x,
                                                      const float* __restrict__ mean,
                                                      const float* __restrict__ rstd,
                                                      const float* __restrict__ rw,
                                                      const float* __restrict__ rb,
                                                      u16* __restrict__ xnT) {
    __shared__ float tile[64][65];
    int d0 = blockIdx.x * 64, s0 = blockIdx.y * 64, b = blockIdx.z;
    for (int e = threadIdx.x; e < 4096; e += 256) {
        int sr = e >> 6, dc = e & 63;
        int d = d0 + dc;
        tile[sr][dc] = (d < DCH) ? x[((size_t)b * SEQL + s0 + sr) * DCH + d] : 0.f;
    }
    __syncthreads();
    for (int e = threadIdx.x; e < 4096; e += 256) {
        int dr = e >> 6, sc = e & 63;
        int d = d0 + dr;
        if (d < DCH) {
            int bd = b * DCH + d;
            float v = (tile[sc][dr] - mean[bd]) * rstd[bd] * rw[d] + rb[d];
            xnT[(size_t)bd * 576 + 32 + s0 + sc] = f2bf(v);
        }
    }
}

__global__ __launch_bounds__(256) void pad_zero(u16* __restrict__ xnT) {
    int idx = blockIdx.x * 256 + threadIdx.x;
    if (idx < BDTOT * 64) {
        int bd = idx >> 6, q = idx & 63;
        int off = q < 32 ? q : 512 + q;   // [0,32) front, [544,576) back
        xnT[(size_t)bd * 576 + off] = 0;
    }
}

// -------- fold matrices: window*DFT*band-MLP layers + irfft, all precomputed --------
__global__ __launch_bounds__(256) void precompute_kernel(
    const float* __restrict__ window,
    const float* __restrict__ l0wr, const float* __restrict__ l0wi,
    const float* __restrict__ l0br, const float* __restrict__ l0bi,
    const float* __restrict__ l1wr, const float* __restrict__ l1wi,
    const float* __restrict__ l1br, const float* __restrict__ l1bi,
    const float* __restrict__ l2wr, const float* __restrict__ l2wi,
    const float* __restrict__ l2br, const float* __restrict__ l2bi,
    const float* __restrict__ m0wr, const float* __restrict__ m0wi,
    const float* __restrict__ m0br, const float* __restrict__ m0bi,
    const float* __restrict__ m1wr, const float* __restrict__ m1wi,
    const float* __restrict__ m1br, const float* __restrict__ m1bi,
    const float* __restrict__ h0wr, const float* __restrict__ h0wi,
    const float* __restrict__ h0br, const float* __restrict__ h0bi,
    u16* __restrict__ A1t, u16* __restrict__ W1t, u16* __restrict__ B2t,
    float* __restrict__ bias1, float* __restrict__ bias2, float* __restrict__ biast)
{
    int idx = blockIdx.x * 256 + threadIdx.x;
    float nrm = 0.f;
    for (int i = 0; i < 64; ++i) nrm += window[i] * window[i];
    float inv = 1.0f / sqrtf(nrm);
    const float STEP = 6.283185307179586f / 64.f;
    auto Cc = [&](int n, int k) { return  window[n] * inv * cosf(STEP * (float)((k * n) & 63)); };
    auto Ss = [&](int n, int k) { return -window[n] * inv * sinf(STEP * (float)((k * n) & 63)); };
    auto aRe = [&](int k, int n) {
        float sc = (k == 0 || k == 32) ? (1.f / 64.f) : (2.f / 64.f);
        return sc * cosf(STEP * (float)((k * n) & 63));
    };
    auto aIm = [&](int k, int n) {
        if (k == 0 || k == 32) return 0.f;            // numpy irfft ignores Im of bin0/Nyquist
        return -(2.f / 64.f) * sinf(STEP * (float)((k * n) & 63));
    };
    if (idx < 16384) {                                 // A1t [256 rows(pad)][64]
        int j = idx >> 6, n = idx & 63;
        float v = 0.f;
        if (j < 18)                    { for (int k = 0; k < 9;  ++k) v += Cc(n,k)   *l0wr[k*18+j]      - Ss(n,k)   *l0wi[k*18+j]; }
        else if (j < 36)               { int jj=j-18; for (int k = 0; k < 9;  ++k) v += Cc(n,k)   *l0wi[k*18+jj] + Ss(n,k)   *l0wr[k*18+jj]; }
        else if (j >= 64  && j < 90)   { int jj=j-64; for (int k = 0; k < 13; ++k) v += Cc(n,9+k) *m0wr[k*26+jj] - Ss(n,9+k) *m0wi[k*26+jj]; }
        else if (j >= 90  && j < 116)  { int jj=j-90; for (int k = 0; k < 13; ++k) v += Cc(n,9+k) *m0wi[k*26+jj] + Ss(n,9+k) *m0wr[k*26+jj]; }
        else if (j >= 128 && j < 139)  { int jj=j-128;for (int k = 0; k < 11; ++k) v += Cc(n,22+k)*h0wr[k*11+jj] - Ss(n,22+k)*h0wi[k*11+jj]; }
        else if (j >= 139 && j < 150)  { int jj=j-139;for (int k = 0; k < 11; ++k) v += Cc(n,22+k)*h0wi[k*11+jj] + Ss(n,22+k)*h0wr[k*11+jj]; }
        A1t[idx] = f2bf(v);
    } else if (idx < 24576) {                          // W1t [128(pad)][64]: low1 as real 36x36
        int t = idx - 16384; int j = t >> 6, k = t & 63;
        float v = 0.f;
        if (j < 18)      { if (k < 18) v = l1wr[k*18+j];        else if (k < 36) v = -l1wi[(k-18)*18+j]; }
        else if (j < 36) { int jj=j-18; if (k < 18) v = l1wi[k*18+jj]; else if (k < 36) v =  l1wr[(k-18)*18+jj]; }
        W1t[t] = f2bf(v);
    } else if (idx < 49152) {                          // B2t [128(pad)][192]: last layers + irfft
        int t = idx - 24576; int n = t / 192, c = t - n * 192;
        float v = 0.f;
        if (n < 64) {
            if (c < 18)                  { for (int m = 0; m < 9;  ++m) v +=  l2wr[c*9+m]     *aRe(m,n)   + l2wi[c*9+m]     *aIm(m,n); }
            else if (c < 36)             { int cc=c-18; for (int m = 0; m < 9;  ++m) v += -l2wi[cc*9+m]   *aRe(m,n)   + l2wr[cc*9+m]   *aIm(m,n); }
            else if (c >= 64 && c < 90)  { int cc=c-64; for (int m = 0; m < 13; ++m) v +=  m1wr[cc*13+m]  *aRe(9+m,n) + m1wi[cc*13+m]  *aIm(9+m,n); }
            else if (c >= 90 && c < 116) { int cc=c-90; for (int m = 0; m < 13; ++m) v += -m1wi[cc*13+m]  *aRe(9+m,n) + m1wr[cc*13+m]  *aIm(9+m,n); }
            else if (c >= 128 && c < 139){ v = aRe(22 + (c-128), n); }
            else if (c >= 139 && c < 150){ v = aIm(22 + (c-139), n); }
        }
        B2t[t] = f2bf(v);
    } else if (idx < 49344) {                          // bias1[192]
        int c = idx - 49152;
        float v = 0.f;
        if (c < 18) v = l0br[c];
        else if (c < 36) v = l0bi[c-18];
        else if (c >= 64 && c < 90) v = m0br[c-64];
        else if (c >= 90 && c < 116) v = m0bi[c-90];
        bias1[c] = v;
    } else if (idx < 49472) {                          // bias2[128]
        int c = idx - 49344;
        float v = 0.f;
        if (c < 18) v = l1br[c]; else if (c < 36) v = l1bi[c-18];
        bias2[c] = v;
    } else if (idx < 49536) {                          // biast[64]: all final biases thru irfft
        int n = idx - 49472;
        float v = 0.f;
        for (int k = 0; k <= 32; ++k) {
            float br = (k < 9) ? l2br[k] : (k < 22 ? m1br[k-9] : h0br[k-22]);
            float bi = (k < 9) ? l2bi[k] : (k < 22 ? m1bi[k-9] : h0bi[k-22]);
            v += aRe(k, n) * br + aIm(k, n) * bi;
        }
        biast[n] = v;
    }
}

// -------- transpose fp32 W[R][C] -> bf16 Wt[Cpad][R] (rows >= C zero-filled) --------
__global__ __launch_bounds__(256) void wtrans(const float* __restrict__ W, u16* __restrict__ Wt,
                                              int R, int C, int Cpad) {
    __shared__ float t[32][33];
    int c0 = blockIdx.x * 32, r0 = blockIdx.y * 32;
    for (int e = threadIdx.x; e < 1024; e += 256) {
        int rr = e >> 5, cc = e & 31;
        int rg = r0 + rr, cg = c0 + cc;
        t[rr][cc] = (rg < R && cg < C) ? W[(size_t)rg * C + cg] : 0.f;
    }
    __syncthreads();
    for (int e = threadIdx.x; e < 1024; e += 256) {
        int cr = e >> 5, rc = e & 31;
        int cg = c0 + cr, rg = r0 + rc;
        if (cg < Cpad && rg < R) Wt[(size_t)cg * R + rg] = f2bf(t[rc][cr]);
    }
}

// -------- generic 128x128 / BK=64 bf16 MFMA GEMM, B given transposed [Npad][K] --------
// EPI: 0=ACT1(bias+lrelu cols<128, plain cols 128..192), 1=ACT2(bias+lrelu),
//      2=EMB(bias), 3=FC1(bias+lrelu), 4=FC2(bias, fp32 out)
// AWIN: A rows are sliding windows over xnT_pad rows
template <int EPI, int AWIN>
__global__ __launch_bounds__(256) void gemm_bt(
    const u16* __restrict__ A, const u16* __restrict__ Bt,
    const float* __restrict__ bias, void* __restrict__ Cp,
    int Mloc, int N, int K, int lda, int ldc,
    long long a_off, long long c_off)
{
    const int tid  = threadIdx.x;
    const int lane = tid & 63;
    const int wm   = (tid >> 7) & 1;
    const int wn   = (tid >> 6) & 1;
    const int bn0  = blockIdx.x * 128;
    const int bm0  = blockIdx.y * 128;
    __shared__ u16 Als[128 * 64];
    __shared__ u16 Bls[128 * 64];
    fvec4 acc[4][4] = {};

    for (int kt = 0; kt < K; kt += 64) {
#pragma unroll
        for (int i = 0; i < 4; ++i) {
            int idx = i * 256 + tid;
            int r  = idx >> 3;
            int kc = (idx & 7) << 3;
            int rl = bm0 + r; if (rl > Mloc - 1) rl = Mloc - 1;
            const u16* asrc;
            if (AWIN) {
                u32 gr = (u32)(a_off + rl);
                u32 bd = gr / 17u;
                u32 nw = gr - bd * 17u;
                asrc = A + (size_t)bd * 576 + nw * 32 + kt + kc;
            } else {
                asrc = A + (size_t)(a_off + rl) * lda + kt + kc;
            }
            gld16(asrc, &Als[idx * 8]);
            const u16* bsrc = Bt + (size_t)(bn0 + r) * K + kt + kc;
            gld16(bsrc, &Bls[idx * 8]);
        }
        __syncthreads();
#pragma unroll
        for (int kk = 0; kk < 2; ++kk) {
            int ko = kk * 32 + ((lane >> 4) << 3);
            bvec8 af[4], bfr[4];
#pragma unroll
            for (int m = 0; m < 4; ++m)
                af[m] = *(const bvec8*)&Als[(wm * 64 + m * 16 + (lane & 15)) * 64 + ko];
#pragma unroll
            for (int n = 0; n < 4; ++n)
                bfr[n] = *(const bvec8*)&Bls[(wn * 64 + n * 16 + (lane & 15)) * 64 + ko];
#pragma unroll
            for (int m = 0; m < 4; ++m)
#pragma unroll
                for (int n = 0; n < 4; ++n)
                    acc[m][n] = __builtin_amdgcn_mfma_f32_16x16x32_bf16(af[m], bfr[n], acc[m][n], 0, 0, 0);
        }
        __syncthreads();
    }

#pragma unroll
    for (int m = 0; m < 4; ++m) {
        int rbase = bm0 + wm * 64 + m * 16 + ((lane >> 4) << 2);
#pragma unroll
        for (int n = 0; n < 4; ++n) {
            int col = bn0 + wn * 64 + n * 16 + (lane & 15);
            if (col < N) {
                float bs = bias[col];
#pragma unroll
                for (int q = 0; q < 4; ++q) {
                    int rl = rbase + q;
                    if (rl < Mloc) {
                        float v = acc[m][n][q] + bs;
                        if (EPI == 0) { if (col < 128) v = lrelu(v); }
                        else if (EPI == 1 || EPI == 3) v = lrelu(v);
                        size_t off = (size_t)(c_off + rl) * (size_t)ldc + col;
                        if (EPI == 4) ((float*)Cp)[off] = v;
                        else          ((u16*)Cp)[off]  = f2bf(v);
                    }
                }
            }
        }
    }
}

// -------- final: de-norm + transpose (b,d,p) -> out(b,p,d) --------
__global__ __launch_bounds__(256) void final_denorm(const float* __restrict__ Y,
                                                    const float* __restrict__ mean,
                                                    const float* __restrict__ stdv,
                                                    const float* __restrict__ rw,
                                                    const float* __restrict__ rb,
                                                    float* __restrict__ out) {
    __shared__ float t[32][33];
    int d0 = blockIdx.x * 32, p0 = blockIdx.y * 32, b = blockIdx.z;
    for (int e = threadIdx.x; e < 1024; e += 256) {
        int di = e >> 5, pj = e & 31;
        int d = d0 + di, p = p0 + pj;
        t[di][pj] = (d < DCH && p < PREDL) ? Y[((size_t)b * DCH + d) * PREDL + p] : 0.f;
    }
    __syncthreads();
    for (int e = threadIdx.x; e < 1024; e += 256) {
        int pi = e >> 5, dj = e & 31;
        int d = d0 + dj, p = p0 + pi;
        if (d < DCH && p < PREDL) {
            int bd = b * DCH + d;
            float v = (t[dj][pi] - rb[d]) / (rw[d] + 1e-10f) * stdv[bd] + mean[bd];
            out[((size_t)b * PREDL + p) * DCH + d] = v;
        }
    }
}

extern "C" void kernel_launch(void* const* d_in, const int* in_sizes, int n_in,
                              void* d_out, int out_size, void* d_ws, size_t ws_size,
                              hipStream_t stream) {
    const float* x      = (const float*)d_in[0];
    const float* window = (const float*)d_in[4];
    const float* rw     = (const float*)d_in[5];
    const float* rb     = (const float*)d_in[6];
    const float* l0wr = (const float*)d_in[7],  *l0wi = (const float*)d_in[8];
    const float* l0br = (const float*)d_in[9],  *l0bi = (const float*)d_in[10];
    const float* l1wr = (const float*)d_in[11], *l1wi = (const float*)d_in[12];
    const float* l1br = (const float*)d_in[13], *l1bi = (const float*)d_in[14];
    const float* l2wr = (const float*)d_in[15], *l2wi = (const float*)d_in[16];
    const float* l2br = (const float*)d_in[17], *l2bi = (const float*)d_in[18];
    const float* m0wr = (const float*)d_in[19], *m0wi = (const float*)d_in[20];
    const float* m0br = (const float*)d_in[21], *m0bi = (const float*)d_in[22];
    const float* m1wr = (const float*)d_in[23], *m1wi = (const float*)d_in[24];
    const float* m1br = (const float*)d_in[25], *m1bi = (const float*)d_in[26];
    const float* h0wr = (const float*)d_in[27], *h0wi = (const float*)d_in[28];
    const float* h0br = (const float*)d_in[29], *h0bi = (const float*)d_in[30];
    const float* fc1w = (const float*)d_in[31];
    const float* fc1b = (const float*)d_in[32];
    const float* fc2w = (const float*)d_in[33];
    const float* fc2b = (const float*)d_in[34];

    char* p = (char*)d_ws;
    auto alloc = [&](size_t n) { char* r = p; p += (n + 255) & ~(size_t)255; return r; };
    float* mean  = (float*)alloc(BDTOT * 4);
    float* rstd  = (float*)alloc(BDTOT * 4);
    float* stdv  = (float*)alloc(BDTOT * 4);
    float* bias1 = (float*)alloc(192 * 4);
    float* bias2 = (float*)alloc(128 * 4);
    float* biast = (float*)alloc(64 * 4);
    u16* A1t   = (u16*)alloc(256 * 64 * 2);
    u16* W1t   = (u16*)alloc(128 * 64 * 2);
    u16* B2t   = (u16*)alloc(128 * 192 * 2);
    u16* fc1wT = (u16*)alloc((size_t)2048 * 1088 * 2);
    u16* fc2wT = (u16*)alloc((size_t)128 * 2048 * 2);
    u16* xnT   = (u16*)alloc((size_t)BDTOT * 576 * 2);   // dead after gemm1 phase
    float* Y   = (float*)xnT;                            // alias: Y (7.9MB) < xnT (23.7MB)
    u16* EMB   = (u16*)alloc((size_t)BDTOT * 1088 * 2);

    size_t fixed_end = (size_t)(p - (char*)d_ws);
    int CH = 16;
    const int chs[5] = {1, 2, 4, 8, 16};
    for (int ci = 0; ci < 5; ++ci) {
        int c = chs[ci];
        size_t act1 = (size_t)(BDTOT / c) * 17 * 192 * 2;
        size_t hbuf = (size_t)(BDTOT / c) * 2048 * 2;
        size_t reg  = act1 > hbuf ? act1 : hbuf;
        if (fixed_end + reg <= ws_size) { CH = c; break; }
    }
    int bd_c = BDTOT / CH;
    int Mw_c = bd_c * 17;
    u16* ACT1 = (u16*)p;      // chunk region, shared by ACT1 / H (disjoint lifetimes)
    u16* Hbuf = ACT1;

    dim3 blk(256);
    stats_kernel<<<BDTOT / 64, blk, 0, stream>>>(x, mean, rstd, stdv);
    norm_transpose<<<dim3(6, 8, NB), blk, 0, stream>>>(x, mean, rstd, rw, rb, xnT);
    pad_zero<<<(BDTOT * 64 + 255) / 256, blk, 0, stream>>>(xnT);
    precompute_kernel<<<194, blk, 0, stream>>>(window,
        l0wr, l0wi, l0br, l0bi, l1wr, l1wi, l1br, l1bi, l2wr, l2wi, l2br, l2bi,
        m0wr, m0wi, m0br, m0bi, m1wr, m1wi, m1br, m1bi, h0wr, h0wi, h0br, h0bi,
        A1t, W1t, B2t, bias1, bias2, biast);
    wtrans<<<dim3(64, 34), blk, 0, stream>>>(fc1w, fc1wT, 1088, 2048, 2048);
    wtrans<<<dim3(4, 64),  blk, 0, stream>>>(fc2w, fc2wT, 2048, 96, 128);

    for (int c = 0; c < CH; ++c) {
        long long aoff = (long long)c * Mw_c;
        int gm = (Mw_c + 127) / 128;
        gemm_bt<0, 1><<<dim3(2, gm), blk, 0, stream>>>(xnT, A1t, bias1, ACT1, Mw_c, 192, 64, 0, 192, aoff, 0);
        gemm_bt<1, 0><<<dim3(1, gm), blk, 0, stream>>>(ACT1, W1t, bias2, ACT1, Mw_c, 64, 64, 192, 192, 0, 0);
        gemm_bt<2, 0><<<dim3(1, gm), blk, 0, stream>>>(ACT1, B2t, biast, EMB, Mw_c, 64, 192, 192, 64, 0, aoff);
    }
    for (int c = 0; c < CH; ++c) {
        long long boff = (long long)c * bd_c;
        int gm = (bd_c + 127) / 128;
        gemm_bt<3, 0><<<dim3(16, gm), blk, 0, stream>>>(EMB, fc1wT, fc1b, Hbuf, bd_c, 2048, 1088, 1088, 2048, boff, 0);
        gemm_bt<4, 0><<<dim3(1, gm), blk, 0, stream>>>(Hbuf, fc2wT, fc2b, Y, bd_c, 96, 2048, 2048, 96, 0, boff);
    }
    final_denorm<<<dim3(11, 3, NB), blk, 0, stream>>>(Y, mean, stdv, rw, rb, (float*)d_out);
}

// Round 2
// 383.554 us; speedup vs baseline: 1.6836x; 1.6836x over previous
//
#include <hip/hip_runtime.h>

typedef unsigned short u16;
typedef unsigned int   u32;
typedef __attribute__((ext_vector_type(4))) float  fvec4;
typedef __attribute__((ext_vector_type(8))) __bf16 bvec8;

#define NB    64
#define SEQL  512
#define DCH   321
#define BDTOT (NB * DCH)      /* 20544 */
#define NWIN  17
#define PREDL 96
#define MWTOT (BDTOT * NWIN)  /* 349248 */

__device__ __forceinline__ u16 f2bf(float f) {
    union { float f; u32 u; } v; v.f = f;
    u32 r = v.u + 0x7FFFu + ((v.u >> 16) & 1u);
    return (u16)(r >> 16);
}
__device__ __forceinline__ float lrelu(float v) { return v > 0.f ? v : 0.01f * v; }

__device__ __forceinline__ void gld16(const u16* g, u16* l) {
    __builtin_amdgcn_global_load_lds((const __attribute__((address_space(1))) void*)g,
                                     (__attribute__((address_space(3))) void*)l, 16, 0, 0);
}

// ---------------- stats: mean / rstd / std per (b,d) over SEQ ----------------
__global__ __launch_bounds__(256) void stats_kernel(const float* __restrict__ x,
                                                    float* __restrict__ mean,
                                                    float* __restrict__ rstd,
                                                    float* __restrict__ stdv) {
    __shared__ float ls[2][4][64];
    int i = threadIdx.x & 63;
    int j = threadIdx.x >> 6;
    int bd = blockIdx.x * 64 + i;
    int b = bd / DCH, d = bd - b * DCH;
    float s = 0.f, ss = 0.f;
    for (int t = j; t < SEQL; t += 4) {
        float v = x[((size_t)b * SEQL + t) * DCH + d];
        s += v; ss += v * v;
    }
    ls[0][j][i] = s; ls[1][j][i] = ss;
    __syncthreads();
    if (j == 0) {
        s  = ls[0][0][i] + ls[0][1][i] + ls[0][2][i] + ls[0][3][i];
        ss = ls[1][0][i] + ls[1][1][i] + ls[1][2][i] + ls[1][3][i];
        float m   = s * (1.f / SEQL);
        float var = ss * (1.f / SEQL) - m * m;
        float st  = sqrtf(var + 1e-5f);
        mean[bd] = m; rstd[bd] = 1.f / st; stdv[bd] = st;
    }
}

// -------- normalize + transpose: x(B,SEQ,D) -> xnT(B*D, 576) bf16, +32 pad --------
__global__ __launch_bounds__(256) void norm_transpose(const float* __restrict__ x,
                                                      const float* __restrict__ mean,
                                                      const float* __restrict__ rstd,
                                                      const float* __restrict__ rw,
                                                      const float* __restrict__ rb,
                                                      u16* __restrict__ xnT) {
    __shared__ float tile[64][65];
    int d0 = blockIdx.x * 64, s0 = blockIdx.y * 64, b = blockIdx.z;
    for (int e = threadIdx.x; e < 4096; e += 256) {
        int sr = e >> 6, dc = e & 63;
        int d = d0 + dc;
        tile[sr][dc] = (d < DCH) ? x[((size_t)b * SEQL + s0 + sr) * DCH + d] : 0.f;
    }
    __syncthreads();
    for (int e = threadIdx.x; e < 4096; e += 256) {
        int dr = e >> 6, sc = e & 63;
        int d = d0 + dr;
        if (d < DCH) {
            int bd = b * DCH + d;
            float v = (tile[sc][dr] - mean[bd]) * rstd[bd] * rw[d] + rb[d];
            xnT[(size_t)bd * 576 + 32 + s0 + sc] = f2bf(v);
        }
    }
}

__global__ __launch_bounds__(256) void pad_zero(u16* __restrict__ xnT) {
    int idx = blockIdx.x * 256 + threadIdx.x;
    if (idx < BDTOT * 64) {
        int bd = idx >> 6, q = idx & 63;
        int off = q < 32 ? q : 512 + q;   // [0,32) front, [544,576) back
        xnT[(size_t)bd * 576 + off] = 0;
    }
}

// -------- fold matrices: window*DFT*band-MLP layers + irfft, all precomputed --------
__global__ __launch_bounds__(256) void precompute_kernel(
    const float* __restrict__ window,
    const float* __restrict__ l0wr, const float* __restrict__ l0wi,
    const float* __restrict__ l0br, const float* __restrict__ l0bi,
    const float* __restrict__ l1wr, const float* __restrict__ l1wi,
    const float* __restrict__ l1br, const float* __restrict__ l1bi,
    const float* __restrict__ l2wr, const float* __restrict__ l2wi,
    const float* __restrict__ l2br, const float* __restrict__ l2bi,
    const float* __restrict__ m0wr, const float* __restrict__ m0wi,
    const float* __restrict__ m0br, const float* __restrict__ m0bi,
    const float* __restrict__ m1wr, const float* __restrict__ m1wi,
    const float* __restrict__ m1br, const float* __restrict__ m1bi,
    const float* __restrict__ h0wr, const float* __restrict__ h0wi,
    const float* __restrict__ h0br, const float* __restrict__ h0bi,
    u16* __restrict__ A1t, u16* __restrict__ W1t, u16* __restrict__ B2t,
    float* __restrict__ bias1, float* __restrict__ bias2, float* __restrict__ biast)
{
    int idx = blockIdx.x * 256 + threadIdx.x;
    float nrm = 0.f;
    for (int i = 0; i < 64; ++i) nrm += window[i] * window[i];
    float inv = 1.0f / sqrtf(nrm);
    const float STEP = 6.283185307179586f / 64.f;
    auto Cc = [&](int n, int k) { return  window[n] * inv * cosf(STEP * (float)((k * n) & 63)); };
    auto Ss = [&](int n, int k) { return -window[n] * inv * sinf(STEP * (float)((k * n) & 63)); };
    auto aRe = [&](int k, int n) {
        float sc = (k == 0 || k == 32) ? (1.f / 64.f) : (2.f / 64.f);
        return sc * cosf(STEP * (float)((k * n) & 63));
    };
    auto aIm = [&](int k, int n) {
        if (k == 0 || k == 32) return 0.f;            // numpy irfft ignores Im of bin0/Nyquist
        return -(2.f / 64.f) * sinf(STEP * (float)((k * n) & 63));
    };
    if (idx < 16384) {                                 // A1t [256 rows(pad)][64]
        int j = idx >> 6, n = idx & 63;
        float v = 0.f;
        if (j < 18)                    { for (int k = 0; k < 9;  ++k) v += Cc(n,k)   *l0wr[k*18+j]      - Ss(n,k)   *l0wi[k*18+j]; }
        else if (j < 36)               { int jj=j-18; for (int k = 0; k < 9;  ++k) v += Cc(n,k)   *l0wi[k*18+jj] + Ss(n,k)   *l0wr[k*18+jj]; }
        else if (j >= 64  && j < 90)   { int jj=j-64; for (int k = 0; k < 13; ++k) v += Cc(n,9+k) *m0wr[k*26+jj] - Ss(n,9+k) *m0wi[k*26+jj]; }
        else if (j >= 90  && j < 116)  { int jj=j-90; for (int k = 0; k < 13; ++k) v += Cc(n,9+k) *m0wi[k*26+jj] + Ss(n,9+k) *m0wr[k*26+jj]; }
        else if (j >= 128 && j < 139)  { int jj=j-128;for (int k = 0; k < 11; ++k) v += Cc(n,22+k)*h0wr[k*11+jj] - Ss(n,22+k)*h0wi[k*11+jj]; }
        else if (j >= 139 && j < 150)  { int jj=j-139;for (int k = 0; k < 11; ++k) v += Cc(n,22+k)*h0wi[k*11+jj] + Ss(n,22+k)*h0wr[k*11+jj]; }
        A1t[idx] = f2bf(v);
    } else if (idx < 24576) {                          // W1t [128(pad)][64]: low1 as real 36x36
        int t = idx - 16384; int j = t >> 6, k = t & 63;
        float v = 0.f;
        if (j < 18)      { if (k < 18) v = l1wr[k*18+j];        else if (k < 36) v = -l1wi[(k-18)*18+j]; }
        else if (j < 36) { int jj=j-18; if (k < 18) v = l1wi[k*18+jj]; else if (k < 36) v =  l1wr[(k-18)*18+jj]; }
        W1t[t] = f2bf(v);
    } else if (idx < 49152) {                          // B2t [128(pad)][192]: last layers + irfft
        int t = idx - 24576; int n = t / 192, c = t - n * 192;
        float v = 0.f;
        if (n < 64) {
            if (c < 18)                  { for (int m = 0; m < 9;  ++m) v +=  l2wr[c*9+m]     *aRe(m,n)   + l2wi[c*9+m]     *aIm(m,n); }
            else if (c < 36)             { int cc=c-18; for (int m = 0; m < 9;  ++m) v += -l2wi[cc*9+m]   *aRe(m,n)   + l2wr[cc*9+m]   *aIm(m,n); }
            else if (c >= 64 && c < 90)  { int cc=c-64; for (int m = 0; m < 13; ++m) v +=  m1wr[cc*13+m]  *aRe(9+m,n) + m1wi[cc*13+m]  *aIm(9+m,n); }
            else if (c >= 90 && c < 116) { int cc=c-90; for (int m = 0; m < 13; ++m) v += -m1wi[cc*13+m]  *aRe(9+m,n) + m1wr[cc*13+m]  *aIm(9+m,n); }
            else if (c >= 128 && c < 139){ v = aRe(22 + (c-128), n); }
            else if (c >= 139 && c < 150){ v = aIm(22 + (c-139), n); }
        }
        B2t[t] = f2bf(v);
    } else if (idx < 49344) {                          // bias1[192]
        int c = idx - 49152;
        float v = 0.f;
        if (c < 18) v = l0br[c];
        else if (c < 36) v = l0bi[c-18];
        else if (c >= 64 && c < 90) v = m0br[c-64];
        else if (c >= 90 && c < 116) v = m0bi[c-90];
        bias1[c] = v;
    } else if (idx < 49472) {                          // bias2[128]
        int c = idx - 49344;
        float v = 0.f;
        if (c < 18) v = l1br[c]; else if (c < 36) v = l1bi[c-18];
        bias2[c] = v;
    } else if (idx < 49536) {                          // biast[64]: all final biases thru irfft
        int n = idx - 49472;
        float v = 0.f;
        for (int k = 0; k <= 32; ++k) {
            float br = (k < 9) ? l2br[k] : (k < 22 ? m1br[k-9] : h0br[k-22]);
            float bi = (k < 9) ? l2bi[k] : (k < 22 ? m1bi[k-9] : h0bi[k-22]);
            v += aRe(k, n) * br + aIm(k, n) * bi;
        }
        biast[n] = v;
    }
}

// -------- transpose fp32 W[R][C] -> bf16 Wt[Cpad][R] (rows >= C zero-filled) --------
__global__ __launch_bounds__(256) void wtrans(const float* __restrict__ W, u16* __restrict__ Wt,
                                              int R, int C, int Cpad) {
    __shared__ float t[32][33];
    int c0 = blockIdx.x * 32, r0 = blockIdx.y * 32;
    for (int e = threadIdx.x; e < 1024; e += 256) {
        int rr = e >> 5, cc = e & 31;
        int rg = r0 + rr, cg = c0 + cc;
        t[rr][cc] = (rg < R && cg < C) ? W[(size_t)rg * C + cg] : 0.f;
    }
    __syncthreads();
    for (int e = threadIdx.x; e < 1024; e += 256) {
        int cr = e >> 5, rc = e & 31;
        int cg = c0 + cr, rg = r0 + rc;
        if (cg < Cpad && rg < R) Wt[(size_t)cg * R + rg] = f2bf(t[rc][cr]);
    }
}

// -------- fused spectral: windows -> stage1(192) -> stage2(low) -> stage3+irfft -> EMB --------
// 64 window-rows per block, 4 waves = 4 N-slices. ACT tile in LDS (stride 208, 4-way max).
__global__ __launch_bounds__(256) void spectral_fused(
    const u16* __restrict__ xnT, const u16* __restrict__ A1t,
    const u16* __restrict__ W1t, const u16* __restrict__ B2t,
    const float* __restrict__ bias1, const float* __restrict__ bias2,
    const float* __restrict__ biast, u16* __restrict__ EMB)
{
    __shared__ u16 XB[64 * 72];     // 9 KB, window rows (stride 72: conflict-free)
    __shared__ u16 ACT[64 * 208];   // 26 KB, stage outputs (stride 208: ~4-way)
    const int tid  = threadIdx.x;
    const int lane = tid & 63;
    const int wn   = tid >> 6;            // 0..3
    const int r0   = blockIdx.x * 64;     // global window-row base (grid divides exactly)

    {   // stage window rows -> XB
        int rr = tid >> 2;
        int cc = (tid & 3) * 16;
        u32 gr = (u32)(r0 + rr);
        u32 bd = gr / 17u, nw = gr - bd * 17u;
        const u16* src = xnT + (size_t)bd * 576 + nw * 32 + cc;
        *(bvec8*)&XB[rr * 72 + cc]     = *(const bvec8*)(src);
        *(bvec8*)&XB[rr * 72 + cc + 8] = *(const bvec8*)(src + 8);
    }
    __syncthreads();

    // ---- stage 1: ACT[64x192] = window @ A1^T, bias1, lrelu on cols<128 ----
    fvec4 acc1[4][3] = {};
#pragma unroll
    for (int kk = 0; kk < 2; ++kk) {
        int ko = kk * 32 + ((lane >> 4) << 3);
        bvec8 af[4], bf[3];
#pragma unroll
        for (int m = 0; m < 4; ++m)
            af[m] = *(const bvec8*)&XB[(m * 16 + (lane & 15)) * 72 + ko];
#pragma unroll
        for (int n = 0; n < 3; ++n)
            bf[n] = *(const bvec8*)(A1t + (size_t)(wn * 48 + n * 16 + (lane & 15)) * 64 + ko);
#pragma unroll
        for (int m = 0; m < 4; ++m)
#pragma unroll
            for (int n = 0; n < 3; ++n)
                acc1[m][n] = __builtin_amdgcn_mfma_f32_16x16x32_bf16(af[m], bf[n], acc1[m][n], 0, 0, 0);
    }
#pragma unroll
    for (int n = 0; n < 3; ++n) {
        int col = wn * 48 + n * 16 + (lane & 15);
        float bs = bias1[col];
#pragma unroll
        for (int m = 0; m < 4; ++m)
#pragma unroll
            for (int q = 0; q < 4; ++q) {
                int row = m * 16 + ((lane >> 4) << 2) + q;
                float v = acc1[m][n][q] + bs;
                if (col < 128) v = lrelu(v);
                ACT[row * 208 + col] = f2bf(v);
            }
    }
    __syncthreads();

    // ---- stage 2: low1 over K = cols 0..63, output cols 0..63 (in place) ----
    fvec4 acc2[4] = {};
#pragma unroll
    for (int kk = 0; kk < 2; ++kk) {
        int ko = kk * 32 + ((lane >> 4) << 3);
        bvec8 bf = *(const bvec8*)(W1t + (size_t)(wn * 16 + (lane & 15)) * 64 + ko);
#pragma unroll
        for (int m = 0; m < 4; ++m) {
            bvec8 af = *(const bvec8*)&ACT[(m * 16 + (lane & 15)) * 208 + ko];
            acc2[m] = __builtin_amdgcn_mfma_f32_16x16x32_bf16(af, bf, acc2[m], 0, 0, 0);
        }
    }
    __syncthreads();   // all stage-2 reads done before overwrite
    {
        int col = wn * 16 + (lane & 15);
        float bs = bias2[col];
#pragma unroll
        for (int m = 0; m < 4; ++m)
#pragma unroll
            for (int q = 0; q < 4; ++q) {
                int row = m * 16 + ((lane >> 4) << 2) + q;
                ACT[row * 208 + col] = f2bf(lrelu(acc2[m][q] + bs));
            }
    }
    __syncthreads();

    // ---- stage 3: EMB[64x64] = ACT[64x192] @ B2^T + biast ----
    fvec4 acc3[4] = {};
#pragma unroll
    for (int kk = 0; kk < 6; ++kk) {
        int ko = kk * 32 + ((lane >> 4) << 3);
        bvec8 bf = *(const bvec8*)(B2t + (size_t)(wn * 16 + (lane & 15)) * 192 + ko);
#pragma unroll
        for (int m = 0; m < 4; ++m) {
            bvec8 af = *(const bvec8*)&ACT[(m * 16 + (lane & 15)) * 208 + ko];
            acc3[m] = __builtin_amdgcn_mfma_f32_16x16x32_bf16(af, bf, acc3[m], 0, 0, 0);
        }
    }
    {
        int col = wn * 16 + (lane & 15);
        float bs = biast[col];
#pragma unroll
        for (int m = 0; m < 4; ++m)
#pragma unroll
            for (int q = 0; q < 4; ++q) {
                int row = m * 16 + ((lane >> 4) << 2) + q;
                EMB[(size_t)(r0 + row) * 64 + col] = f2bf(acc3[m][q] + bs);
            }
    }
}

// -------- generic 128x128 / BK=64 bf16 MFMA GEMM, B transposed [Npad][K] --------
// EPI: 3=FC1(bias+lrelu, bf16), 4=FC2 split-K partial (fp32, no bias)
// SWZ: 1D grid with bijective XCD swizzle, nt-fastest (A-panel reuse per XCD)
// SPLITK: blockIdx.x = K-chunk, bn0 = 0, partial out at Cp + x*pstride
template <int EPI, int SWZ, int SPLITK>
__global__ __launch_bounds__(256) void gemm_bt(
    const u16* __restrict__ A, const u16* __restrict__ Bt,
    const float* __restrict__ bias, void* __restrict__ Cp,
    int Mloc, int N, int K, int lda, int ldc,
    long long a_off, long long c_off, int ntn, int nwg, int klen, long long pstride)
{
    const int tid  = threadIdx.x;
    const int lane = tid & 63;
    const int wm   = (tid >> 7) & 1;
    const int wn   = (tid >> 6) & 1;
    int mt, nt, k0 = 0, k1 = K;
    if (SPLITK) {
        nt = 0; mt = blockIdx.y;
        k0 = blockIdx.x * klen;
        k1 = (k0 + klen > K) ? K : k0 + klen;
    } else if (SWZ) {
        int bid = blockIdx.x;
        int q = nwg >> 3, r = nwg & 7, xcd = bid & 7, off = bid >> 3;
        int wg = (xcd < r) ? (xcd * (q + 1) + off) : (r * (q + 1) + (xcd - r) * q + off);
        mt = wg / ntn; nt = wg - mt * ntn;
    } else {
        nt = blockIdx.x; mt = blockIdx.y;
    }
    const int bn0 = nt * 128;
    const int bm0 = mt * 128;
    __shared__ u16 Als[128 * 64];
    __shared__ u16 Bls[128 * 64];
    fvec4 acc[4][4] = {};

    for (int kt = k0; kt < k1; kt += 64) {
#pragma unroll
        for (int i = 0; i < 4; ++i) {
            int idx = i * 256 + tid;
            int r  = idx >> 3;
            int kc = (idx & 7) << 3;
            int rl = bm0 + r; if (rl > Mloc - 1) rl = Mloc - 1;
            gld16(A + (size_t)(a_off + rl) * lda + kt + kc, &Als[idx * 8]);
            gld16(Bt + (size_t)(bn0 + r) * K + kt + kc,     &Bls[idx * 8]);
        }
        __syncthreads();
#pragma unroll
        for (int kk = 0; kk < 2; ++kk) {
            int ko = kk * 32 + ((lane >> 4) << 3);
            bvec8 af[4], bfr[4];
#pragma unroll
            for (int m = 0; m < 4; ++m)
                af[m] = *(const bvec8*)&Als[(wm * 64 + m * 16 + (lane & 15)) * 64 + ko];
#pragma unroll
            for (int n = 0; n < 4; ++n)
                bfr[n] = *(const bvec8*)&Bls[(wn * 64 + n * 16 + (lane & 15)) * 64 + ko];
#pragma unroll
            for (int m = 0; m < 4; ++m)
#pragma unroll
                for (int n = 0; n < 4; ++n)
                    acc[m][n] = __builtin_amdgcn_mfma_f32_16x16x32_bf16(af[m], bfr[n], acc[m][n], 0, 0, 0);
        }
        __syncthreads();
    }

#pragma unroll
    for (int m = 0; m < 4; ++m) {
        int rbase = bm0 + wm * 64 + m * 16 + ((lane >> 4) << 2);
#pragma unroll
        for (int n = 0; n < 4; ++n) {
            int col = bn0 + wn * 64 + n * 16 + (lane & 15);
            if (col < N) {
#pragma unroll
                for (int q = 0; q < 4; ++q) {
                    int rl = rbase + q;
                    if (rl < Mloc) {
                        if (EPI == 4) {
                            float* yp = (float*)Cp + (size_t)blockIdx.x * pstride;
                            yp[(size_t)(c_off + rl) * ldc + col] = acc[m][n][q];
                        } else {
                            float v = lrelu(acc[m][n][q] + bias[col]);
                            ((u16*)Cp)[(size_t)(c_off + rl) * ldc + col] = f2bf(v);
                        }
                    }
                }
            }
        }
    }
}

// -------- final: sum 3 fc2 partials + bias, de-norm + transpose -> out(b,p,d) --------
__global__ __launch_bounds__(256) void final_denorm(const float* __restrict__ YP,
                                                    const float* __restrict__ fc2b,
                                                    const float* __restrict__ mean,
                                                    const float* __restrict__ stdv,
                                                    const float* __restrict__ rw,
                                                    const float* __restrict__ rb,
                                                    float* __restrict__ out) {
    const long long PART = (long long)BDTOT * PREDL;
    __shared__ float t[32][33];
    int d0 = blockIdx.x * 32, p0 = blockIdx.y * 32, b = blockIdx.z;
    for (int e = threadIdx.x; e < 1024; e += 256) {
        int di = e >> 5, pj = e & 31;
        int d = d0 + di, p = p0 + pj;
        if (d < DCH && p < PREDL) {
            size_t off = ((size_t)b * DCH + d) * PREDL + p;
            t[di][pj] = YP[off] + YP[off + PART] + YP[off + 2 * PART] + fc2b[p];
        } else t[di][pj] = 0.f;
    }
    __syncthreads();
    for (int e = threadIdx.x; e < 1024; e += 256) {
        int pi = e >> 5, dj = e & 31;
        int d = d0 + dj, p = p0 + pi;
        if (d < DCH && p < PREDL) {
            int bd = b * DCH + d;
            float v = (t[dj][pi] - rb[d]) / (rw[d] + 1e-10f) * stdv[bd] + mean[bd];
            out[((size_t)b * PREDL + p) * DCH + d] = v;
        }
    }
}

extern "C" void kernel_launch(void* const* d_in, const int* in_sizes, int n_in,
                              void* d_out, int out_size, void* d_ws, size_t ws_size,
                              hipStream_t stream) {
    const float* x      = (const float*)d_in[0];
    const float* window = (const float*)d_in[4];
    const float* rw     = (const float*)d_in[5];
    const float* rb     = (const float*)d_in[6];
    const float* l0wr = (const float*)d_in[7],  *l0wi = (const float*)d_in[8];
    const float* l0br = (const float*)d_in[9],  *l0bi = (const float*)d_in[10];
    const float* l1wr = (const float*)d_in[11], *l1wi = (const float*)d_in[12];
    const float* l1br = (const float*)d_in[13], *l1bi = (const float*)d_in[14];
    const float* l2wr = (const float*)d_in[15], *l2wi = (const float*)d_in[16];
    const float* l2br = (const float*)d_in[17], *l2bi = (const float*)d_in[18];
    const float* m0wr = (const float*)d_in[19], *m0wi = (const float*)d_in[20];
    const float* m0br = (const float*)d_in[21], *m0bi = (const float*)d_in[22];
    const float* m1wr = (const float*)d_in[23], *m1wi = (const float*)d_in[24];
    const float* m1br = (const float*)d_in[25], *m1bi = (const float*)d_in[26];
    const float* h0wr = (const float*)d_in[27], *h0wi = (const float*)d_in[28];
    const float* h0br = (const float*)d_in[29], *h0bi = (const float*)d_in[30];
    const float* fc1w = (const float*)d_in[31];
    const float* fc1b = (const float*)d_in[32];
    const float* fc2w = (const float*)d_in[33];
    const float* fc2b = (const float*)d_in[34];

    char* p = (char*)d_ws;
    auto alloc = [&](size_t n) { char* r = p; p += (n + 255) & ~(size_t)255; return r; };
    float* mean  = (float*)alloc(BDTOT * 4);
    float* rstd  = (float*)alloc(BDTOT * 4);
    float* stdv  = (float*)alloc(BDTOT * 4);
    float* bias1 = (float*)alloc(192 * 4);
    float* bias2 = (float*)alloc(128 * 4);
    float* biast = (float*)alloc(64 * 4);
    u16* A1t   = (u16*)alloc(256 * 64 * 2);
    u16* W1t   = (u16*)alloc(128 * 64 * 2);
    u16* B2t   = (u16*)alloc(128 * 192 * 2);
    u16* fc1wT = (u16*)alloc((size_t)2048 * 1088 * 2);
    u16* fc2wT = (u16*)alloc((size_t)128 * 2048 * 2);
    u16* xnT   = (u16*)alloc((size_t)BDTOT * 576 * 2);   // dead after spectral phase
    float* YP  = (float*)xnT;   // alias: 3 fc2 partials = 3*20544*96*4 == xnT bytes exactly
    u16* EMB   = (u16*)alloc((size_t)BDTOT * 1088 * 2);

    size_t fixed_end = (size_t)(p - (char*)d_ws);
    int CH = 16;
    const int chs[5] = {1, 2, 4, 8, 16};
    for (int ci = 0; ci < 5; ++ci) {
        int c = chs[ci];
        size_t hbuf = (size_t)(BDTOT / c) * 2048 * 2;
        if (fixed_end + hbuf <= ws_size) { CH = c; break; }
    }
    int bd_c = BDTOT / CH;
    u16* Hbuf = (u16*)p;

    dim3 blk(256);
    stats_kernel<<<BDTOT / 64, blk, 0, stream>>>(x, mean, rstd, stdv);
    norm_transpose<<<dim3(6, 8, NB), blk, 0, stream>>>(x, mean, rstd, rw, rb, xnT);
    pad_zero<<<(BDTOT * 64 + 255) / 256, blk, 0, stream>>>(xnT);
    precompute_kernel<<<194, blk, 0, stream>>>(window,
        l0wr, l0wi, l0br, l0bi, l1wr, l1wi, l1br, l1bi, l2wr, l2wi, l2br, l2bi,
        m0wr, m0wi, m0br, m0bi, m1wr, m1wi, m1br, m1bi, h0wr, h0wi, h0br, h0bi,
        A1t, W1t, B2t, bias1, bias2, biast);
    wtrans<<<dim3(64, 34), blk, 0, stream>>>(fc1w, fc1wT, 1088, 2048, 2048);
    wtrans<<<dim3(4, 64),  blk, 0, stream>>>(fc2w, fc2wT, 2048, 96, 128);

    spectral_fused<<<MWTOT / 64, blk, 0, stream>>>(xnT, A1t, W1t, B2t, bias1, bias2, biast, EMB);

    const long long PART = (long long)BDTOT * PREDL;
    for (int c = 0; c < CH; ++c) {
        long long boff = (long long)c * bd_c;
        int gm = (bd_c + 127) / 128;
        int nwg = 16 * gm;
        gemm_bt<3, 1, 0><<<dim3(nwg), blk, 0, stream>>>(EMB, fc1wT, fc1b, Hbuf,
            bd_c, 2048, 1088, 1088, 2048, boff, 0, 16, nwg, 0, 0);
        gemm_bt<4, 0, 1><<<dim3(3, gm), blk, 0, stream>>>(Hbuf, fc2wT, nullptr, YP,
            bd_c, 96, 2048, 2048, 96, 0, boff, 0, 0, 704, PART);
    }
    final_denorm<<<dim3(11, 3, NB), blk, 0, stream>>>(YP, fc2b, mean, stdv, rw, rb, (float*)d_out);
}

// Round 3
// 347.541 us; speedup vs baseline: 1.8581x; 1.1036x over previous
//
#include <hip/hip_runtime.h>

typedef unsigned short u16;
typedef unsigned int   u32;
typedef __attribute__((ext_vector_type(4))) float  fvec4;
typedef __attribute__((ext_vector_type(8))) __bf16 bvec8;

#define NB    64
#define SEQL  512
#define DCH   321
#define BDTOT (NB * DCH)      /* 20544 */
#define NWIN  17
#define PREDL 96
#define MWTOT (BDTOT * NWIN)  /* 349248 */

__device__ __forceinline__ u16 f2bf(float f) {
    union { float f; u32 u; } v; v.f = f;
    u32 r = v.u + 0x7FFFu + ((v.u >> 16) & 1u);
    return (u16)(r >> 16);
}
__device__ __forceinline__ float lrelu(float v) { return v > 0.f ? v : 0.01f * v; }

__device__ __forceinline__ void gld16(const u16* g, u16* l) {
    __builtin_amdgcn_global_load_lds((const __attribute__((address_space(1))) void*)g,
                                     (__attribute__((address_space(3))) void*)l, 16, 0, 0);
}

// ---------------- stats: mean / rstd / std per (b,d) over SEQ ----------------
__global__ __launch_bounds__(256) void stats_kernel(const float* __restrict__ x,
                                                    float* __restrict__ mean,
                                                    float* __restrict__ rstd,
                                                    float* __restrict__ stdv) {
    __shared__ float ls[2][4][64];
    int i = threadIdx.x & 63;
    int j = threadIdx.x >> 6;
    int bd = blockIdx.x * 64 + i;
    int b = bd / DCH, d = bd - b * DCH;
    float s = 0.f, ss = 0.f;
    for (int t = j; t < SEQL; t += 4) {
        float v = x[((size_t)b * SEQL + t) * DCH + d];
        s += v; ss += v * v;
    }
    ls[0][j][i] = s; ls[1][j][i] = ss;
    __syncthreads();
    if (j == 0) {
        s  = ls[0][0][i] + ls[0][1][i] + ls[0][2][i] + ls[0][3][i];
        ss = ls[1][0][i] + ls[1][1][i] + ls[1][2][i] + ls[1][3][i];
        float m   = s * (1.f / SEQL);
        float var = ss * (1.f / SEQL) - m * m;
        float st  = sqrtf(var + 1e-5f);
        mean[bd] = m; rstd[bd] = 1.f / st; stdv[bd] = st;
    }
}

// -------- normalize + transpose: x(B,SEQ,D) -> xnT(B*D, 576) bf16, +32 pad --------
__global__ __launch_bounds__(256) void norm_transpose(const float* __restrict__ x,
                                                      const float* __restrict__ mean,
                                                      const float* __restrict__ rstd,
                                                      const float* __restrict__ rw,
                                                      const float* __restrict__ rb,
                                                      u16* __restrict__ xnT) {
    __shared__ float tile[64][65];
    int d0 = blockIdx.x * 64, s0 = blockIdx.y * 64, b = blockIdx.z;
    for (int e = threadIdx.x; e < 4096; e += 256) {
        int sr = e >> 6, dc = e & 63;
        int d = d0 + dc;
        tile[sr][dc] = (d < DCH) ? x[((size_t)b * SEQL + s0 + sr) * DCH + d] : 0.f;
    }
    __syncthreads();
    for (int e = threadIdx.x; e < 4096; e += 256) {
        int dr = e >> 6, sc = e & 63;
        int d = d0 + dr;
        if (d < DCH) {
            int bd = b * DCH + d;
            float v = (tile[sc][dr] - mean[bd]) * rstd[bd] * rw[d] + rb[d];
            xnT[(size_t)bd * 576 + 32 + s0 + sc] = f2bf(v);
        }
    }
}

__global__ __launch_bounds__(256) void pad_zero(u16* __restrict__ xnT) {
    int idx = blockIdx.x * 256 + threadIdx.x;
    if (idx < BDTOT * 64) {
        int bd = idx >> 6, q = idx & 63;
        int off = q < 32 ? q : 512 + q;   // [0,32) front, [544,576) back
        xnT[(size_t)bd * 576 + off] = 0;
    }
}

// -------- fold matrices: window*DFT*band-MLP layers + irfft, all precomputed --------
__global__ __launch_bounds__(256) void precompute_kernel(
    const float* __restrict__ window,
    const float* __restrict__ l0wr, const float* __restrict__ l0wi,
    const float* __restrict__ l0br, const float* __restrict__ l0bi,
    const float* __restrict__ l1wr, const float* __restrict__ l1wi,
    const float* __restrict__ l1br, const float* __restrict__ l1bi,
    const float* __restrict__ l2wr, const float* __restrict__ l2wi,
    const float* __restrict__ l2br, const float* __restrict__ l2bi,
    const float* __restrict__ m0wr, const float* __restrict__ m0wi,
    const float* __restrict__ m0br, const float* __restrict__ m0bi,
    const float* __restrict__ m1wr, const float* __restrict__ m1wi,
    const float* __restrict__ m1br, const float* __restrict__ m1bi,
    const float* __restrict__ h0wr, const float* __restrict__ h0wi,
    const float* __restrict__ h0br, const float* __restrict__ h0bi,
    u16* __restrict__ A1t, u16* __restrict__ W1t, u16* __restrict__ B2t,
    float* __restrict__ bias1, float* __restrict__ bias2, float* __restrict__ biast)
{
    int idx = blockIdx.x * 256 + threadIdx.x;
    float nrm = 0.f;
    for (int i = 0; i < 64; ++i) nrm += window[i] * window[i];
    float inv = 1.0f / sqrtf(nrm);
    const float STEP = 6.283185307179586f / 64.f;
    auto Cc = [&](int n, int k) { return  window[n] * inv * cosf(STEP * (float)((k * n) & 63)); };
    auto Ss = [&](int n, int k) { return -window[n] * inv * sinf(STEP * (float)((k * n) & 63)); };
    auto aRe = [&](int k, int n) {
        float sc = (k == 0 || k == 32) ? (1.f / 64.f) : (2.f / 64.f);
        return sc * cosf(STEP * (float)((k * n) & 63));
    };
    auto aIm = [&](int k, int n) {
        if (k == 0 || k == 32) return 0.f;            // numpy irfft ignores Im of bin0/Nyquist
        return -(2.f / 64.f) * sinf(STEP * (float)((k * n) & 63));
    };
    if (idx < 16384) {                                 // A1t [256 rows(pad)][64]
        int j = idx >> 6, n = idx & 63;
        float v = 0.f;
        if (j < 18)                    { for (int k = 0; k < 9;  ++k) v += Cc(n,k)   *l0wr[k*18+j]      - Ss(n,k)   *l0wi[k*18+j]; }
        else if (j < 36)               { int jj=j-18; for (int k = 0; k < 9;  ++k) v += Cc(n,k)   *l0wi[k*18+jj] + Ss(n,k)   *l0wr[k*18+jj]; }
        else if (j >= 64  && j < 90)   { int jj=j-64; for (int k = 0; k < 13; ++k) v += Cc(n,9+k) *m0wr[k*26+jj] - Ss(n,9+k) *m0wi[k*26+jj]; }
        else if (j >= 90  && j < 116)  { int jj=j-90; for (int k = 0; k < 13; ++k) v += Cc(n,9+k) *m0wi[k*26+jj] + Ss(n,9+k) *m0wr[k*26+jj]; }
        else if (j >= 128 && j < 139)  { int jj=j-128;for (int k = 0; k < 11; ++k) v += Cc(n,22+k)*h0wr[k*11+jj] - Ss(n,22+k)*h0wi[k*11+jj]; }
        else if (j >= 139 && j < 150)  { int jj=j-139;for (int k = 0; k < 11; ++k) v += Cc(n,22+k)*h0wi[k*11+jj] + Ss(n,22+k)*h0wr[k*11+jj]; }
        A1t[idx] = f2bf(v);
    } else if (idx < 24576) {                          // W1t [128(pad)][64]: low1 as real 36x36
        int t = idx - 16384; int j = t >> 6, k = t & 63;
        float v = 0.f;
        if (j < 18)      { if (k < 18) v = l1wr[k*18+j];        else if (k < 36) v = -l1wi[(k-18)*18+j]; }
        else if (j < 36) { int jj=j-18; if (k < 18) v = l1wi[k*18+jj]; else if (k < 36) v =  l1wr[(k-18)*18+jj]; }
        W1t[t] = f2bf(v);
    } else if (idx < 49152) {                          // B2t [128(pad)][192]: last layers + irfft
        int t = idx - 24576; int n = t / 192, c = t - n * 192;
        float v = 0.f;
        if (n < 64) {
            if (c < 18)                  { for (int m = 0; m < 9;  ++m) v +=  l2wr[c*9+m]     *aRe(m,n)   + l2wi[c*9+m]     *aIm(m,n); }
            else if (c < 36)             { int cc=c-18; for (int m = 0; m < 9;  ++m) v += -l2wi[cc*9+m]   *aRe(m,n)   + l2wr[cc*9+m]   *aIm(m,n); }
            else if (c >= 64 && c < 90)  { int cc=c-64; for (int m = 0; m < 13; ++m) v +=  m1wr[cc*13+m]  *aRe(9+m,n) + m1wi[cc*13+m]  *aIm(9+m,n); }
            else if (c >= 90 && c < 116) { int cc=c-90; for (int m = 0; m < 13; ++m) v += -m1wi[cc*13+m]  *aRe(9+m,n) + m1wr[cc*13+m]  *aIm(9+m,n); }
            else if (c >= 128 && c < 139){ v = aRe(22 + (c-128), n); }
            else if (c >= 139 && c < 150){ v = aIm(22 + (c-139), n); }
        }
        B2t[t] = f2bf(v);
    } else if (idx < 49344) {                          // bias1[192]
        int c = idx - 49152;
        float v = 0.f;
        if (c < 18) v = l0br[c];
        else if (c < 36) v = l0bi[c-18];
        else if (c >= 64 && c < 90) v = m0br[c-64];
        else if (c >= 90 && c < 116) v = m0bi[c-90];
        bias1[c] = v;
    } else if (idx < 49472) {                          // bias2[128]
        int c = idx - 49344;
        float v = 0.f;
        if (c < 18) v = l1br[c]; else if (c < 36) v = l1bi[c-18];
        bias2[c] = v;
    } else if (idx < 49536) {                          // biast[64]: all final biases thru irfft
        int n = idx - 49472;
        float v = 0.f;
        for (int k = 0; k <= 32; ++k) {
            float br = (k < 9) ? l2br[k] : (k < 22 ? m1br[k-9] : h0br[k-22]);
            float bi = (k < 9) ? l2bi[k] : (k < 22 ? m1bi[k-9] : h0bi[k-22]);
            v += aRe(k, n) * br + aIm(k, n) * bi;
        }
        biast[n] = v;
    }
}

// -------- transpose fp32 W[R][C] -> bf16 Wt[Cpad][R] (rows >= C zero-filled) --------
__global__ __launch_bounds__(256) void wtrans(const float* __restrict__ W, u16* __restrict__ Wt,
                                              int R, int C, int Cpad) {
    __shared__ float t[32][33];
    int c0 = blockIdx.x * 32, r0 = blockIdx.y * 32;
    for (int e = threadIdx.x; e < 1024; e += 256) {
        int rr = e >> 5, cc = e & 31;
        int rg = r0 + rr, cg = c0 + cc;
        t[rr][cc] = (rg < R && cg < C) ? W[(size_t)rg * C + cg] : 0.f;
    }
    __syncthreads();
    for (int e = threadIdx.x; e < 1024; e += 256) {
        int cr = e >> 5, rc = e & 31;
        int cg = c0 + cr, rg = r0 + rc;
        if (cg < Cpad && rg < R) Wt[(size_t)cg * R + rg] = f2bf(t[rc][cr]);
    }
}

// -------- fused spectral: windows -> stage1(192) -> stage2(low) -> stage3+irfft -> EMB --------
__global__ __launch_bounds__(256) void spectral_fused(
    const u16* __restrict__ xnT, const u16* __restrict__ A1t,
    const u16* __restrict__ W1t, const u16* __restrict__ B2t,
    const float* __restrict__ bias1, const float* __restrict__ bias2,
    const float* __restrict__ biast, u16* __restrict__ EMB)
{
    __shared__ u16 XB[64 * 72];     // 9 KB, window rows (stride 72: conflict-free)
    __shared__ u16 ACT[64 * 208];   // 26 KB, stage outputs (stride 208: ~4-way)
    const int tid  = threadIdx.x;
    const int lane = tid & 63;
    const int wn   = tid >> 6;            // 0..3
    const int r0   = blockIdx.x * 64;     // global window-row base (grid divides exactly)

    {   // stage window rows -> XB
        int rr = tid >> 2;
        int cc = (tid & 3) * 16;
        u32 gr = (u32)(r0 + rr);
        u32 bd = gr / 17u, nw = gr - bd * 17u;
        const u16* src = xnT + (size_t)bd * 576 + nw * 32 + cc;
        *(bvec8*)&XB[rr * 72 + cc]     = *(const bvec8*)(src);
        *(bvec8*)&XB[rr * 72 + cc + 8] = *(const bvec8*)(src + 8);
    }
    __syncthreads();

    // ---- stage 1: ACT[64x192] = window @ A1^T, bias1, lrelu on cols<128 ----
    fvec4 acc1[4][3] = {};
#pragma unroll
    for (int kk = 0; kk < 2; ++kk) {
        int ko = kk * 32 + ((lane >> 4) << 3);
        bvec8 af[4], bf[3];
#pragma unroll
        for (int m = 0; m < 4; ++m)
            af[m] = *(const bvec8*)&XB[(m * 16 + (lane & 15)) * 72 + ko];
#pragma unroll
        for (int n = 0; n < 3; ++n)
            bf[n] = *(const bvec8*)(A1t + (size_t)(wn * 48 + n * 16 + (lane & 15)) * 64 + ko);
#pragma unroll
        for (int m = 0; m < 4; ++m)
#pragma unroll
            for (int n = 0; n < 3; ++n)
                acc1[m][n] = __builtin_amdgcn_mfma_f32_16x16x32_bf16(af[m], bf[n], acc1[m][n], 0, 0, 0);
    }
#pragma unroll
    for (int n = 0; n < 3; ++n) {
        int col = wn * 48 + n * 16 + (lane & 15);
        float bs = bias1[col];
#pragma unroll
        for (int m = 0; m < 4; ++m)
#pragma unroll
            for (int q = 0; q < 4; ++q) {
                int row = m * 16 + ((lane >> 4) << 2) + q;
                float v = acc1[m][n][q] + bs;
                if (col < 128) v = lrelu(v);
                ACT[row * 208 + col] = f2bf(v);
            }
    }
    __syncthreads();

    // ---- stage 2: low1 over K = cols 0..63, output cols 0..63 (in place) ----
    fvec4 acc2[4] = {};
#pragma unroll
    for (int kk = 0; kk < 2; ++kk) {
        int ko = kk * 32 + ((lane >> 4) << 3);
        bvec8 bf = *(const bvec8*)(W1t + (size_t)(wn * 16 + (lane & 15)) * 64 + ko);
#pragma unroll
        for (int m = 0; m < 4; ++m) {
            bvec8 af = *(const bvec8*)&ACT[(m * 16 + (lane & 15)) * 208 + ko];
            acc2[m] = __builtin_amdgcn_mfma_f32_16x16x32_bf16(af, bf, acc2[m], 0, 0, 0);
        }
    }
    __syncthreads();   // all stage-2 reads done before overwrite
    {
        int col = wn * 16 + (lane & 15);
        float bs = bias2[col];
#pragma unroll
        for (int m = 0; m < 4; ++m)
#pragma unroll
            for (int q = 0; q < 4; ++q) {
                int row = m * 16 + ((lane >> 4) << 2) + q;
                ACT[row * 208 + col] = f2bf(lrelu(acc2[m][q] + bs));
            }
    }
    __syncthreads();

    // ---- stage 3: EMB[64x64] = ACT[64x192] @ B2^T + biast ----
    fvec4 acc3[4] = {};
#pragma unroll
    for (int kk = 0; kk < 6; ++kk) {
        int ko = kk * 32 + ((lane >> 4) << 3);
        bvec8 bf = *(const bvec8*)(B2t + (size_t)(wn * 16 + (lane & 15)) * 192 + ko);
#pragma unroll
        for (int m = 0; m < 4; ++m) {
            bvec8 af = *(const bvec8*)&ACT[(m * 16 + (lane & 15)) * 208 + ko];
            acc3[m] = __builtin_amdgcn_mfma_f32_16x16x32_bf16(af, bf, acc3[m], 0, 0, 0);
        }
    }
    {
        int col = wn * 16 + (lane & 15);
        float bs = biast[col];
#pragma unroll
        for (int m = 0; m < 4; ++m)
#pragma unroll
            for (int q = 0; q < 4; ++q) {
                int row = m * 16 + ((lane >> 4) << 2) + q;
                EMB[(size_t)(r0 + row) * 64 + col] = f2bf(acc3[m][q] + bs);
            }
    }
}

// ======== fc1: 256x256 / BK=64 / 512-thread 2-phase double-buffered GEMM ========
// Catalog "minimum 2-phase": STAGE(next) issued BEFORE compute(cur); one counted
// vmcnt(8) + barrier pair per K-tile (next tile's 8 loads stay in flight).
// 8 waves (2M x 4N), per-wave C = 128x64 (acc[8][4]). Dynamic LDS 128 KiB.
template <int SWZ>
__global__ __launch_bounds__(512, 2) void gemm256(
    const u16* __restrict__ A, const u16* __restrict__ Bt,
    const float* __restrict__ bias, u16* __restrict__ C,
    int Mloc, int K, int ldc, long long a_off, int nwg)
{
    extern __shared__ u16 lds[];            // [2][A 16384 | B 16384]
    const int tid  = threadIdx.x;
    const int lane = tid & 63;
    const int wid  = tid >> 6;
    const int wm   = wid >> 2;              // 0..1
    const int wn   = wid & 3;               // 0..3
    int wg;
    if (SWZ) {
        int bid = blockIdx.x;
        int q = nwg >> 3, r = nwg & 7, xcd = bid & 7, off = bid >> 3;
        wg = (xcd < r) ? (xcd * (q + 1) + off) : (r * (q + 1) + (xcd - r) * q + off);
    } else wg = blockIdx.x;
    const int mt = wg >> 3;                 // N = 2048 -> 8 n-tiles, nt-fastest
    const int nt = wg & 7;
    const int bm0 = mt * 256, bn0 = nt * 256;

    auto stage = [&](int bufb, int kt) {
        u16* dstA = lds + bufb * 32768;
        u16* dstB = dstA + 16384;
#pragma unroll
        for (int j = 0; j < 4; ++j) {
            int idx = j * 512 + tid;
            int r  = idx >> 3;
            int kc = (idx & 7) << 3;
            int rl = bm0 + r; if (rl > Mloc - 1) rl = Mloc - 1;
            gld16(A  + (size_t)(a_off + rl) * K + kt + kc, dstA + idx * 8);
            gld16(Bt + (size_t)(bn0 + r)   * K + kt + kc, dstB + idx * 8);
        }
    };

    fvec4 acc[8][4] = {};

    auto compute = [&](int bufb) {
        const u16* Ab = lds + bufb * 32768;
        const u16* Bb = Ab + 16384;
        __builtin_amdgcn_s_setprio(1);
#pragma unroll
        for (int kk = 0; kk < 2; ++kk) {
            int ko = kk * 32 + ((lane >> 4) << 3);
            bvec8 af[8], bf[4];
#pragma unroll
            for (int m = 0; m < 8; ++m)
                af[m] = *(const bvec8*)&Ab[(wm * 128 + m * 16 + (lane & 15)) * 64 + ko];
#pragma unroll
            for (int n = 0; n < 4; ++n)
                bf[n] = *(const bvec8*)&Bb[(wn * 64 + n * 16 + (lane & 15)) * 64 + ko];
#pragma unroll
            for (int m = 0; m < 8; ++m)
#pragma unroll
                for (int n = 0; n < 4; ++n)
                    acc[m][n] = __builtin_amdgcn_mfma_f32_16x16x32_bf16(af[m], bf[n], acc[m][n], 0, 0, 0);
        }
        __builtin_amdgcn_s_setprio(0);
    };

    const int NT = K >> 6;                  // 1088 -> 17
    stage(0, 0);
    int cur = 0;
    for (int t = 0; t < NT - 1; ++t) {
        stage(cur ^ 1, (t + 1) << 6);       // issue next tile first (overlaps compute)
        asm volatile("s_waitcnt vmcnt(8)" ::: "memory");
        __builtin_amdgcn_sched_barrier(0);
        __builtin_amdgcn_s_barrier();
        __builtin_amdgcn_sched_barrier(0);
        compute(cur);
        __builtin_amdgcn_sched_barrier(0);
        __builtin_amdgcn_s_barrier();
        __builtin_amdgcn_sched_barrier(0);
        cur ^= 1;
    }
    asm volatile("s_waitcnt vmcnt(0)" ::: "memory");
    __builtin_amdgcn_sched_barrier(0);
    __builtin_amdgcn_s_barrier();
    __builtin_amdgcn_sched_barrier(0);
    compute(cur);

    // epilogue: bias + lrelu -> bf16
#pragma unroll
    for (int m = 0; m < 8; ++m) {
        int rl0 = bm0 + wm * 128 + m * 16 + ((lane >> 4) << 2);
#pragma unroll
        for (int n = 0; n < 4; ++n) {
            int col = bn0 + wn * 64 + n * 16 + (lane & 15);
            float bs = bias[col];
#pragma unroll
            for (int q = 0; q < 4; ++q) {
                int rl = rl0 + q;
                if (rl < Mloc)
                    C[(size_t)rl * (size_t)ldc + col] = f2bf(lrelu(acc[m][n][q] + bs));
            }
        }
    }
}

// -------- 128x128 / BK=64 GEMM, fc2 split-K partial (fp32 out, no bias) --------
__global__ __launch_bounds__(256) void gemm_bt_splitk(
    const u16* __restrict__ A, const u16* __restrict__ Bt,
    void* __restrict__ Cp, int Mloc, int N, int K, int lda, int ldc,
    long long c_off, int klen, long long pstride)
{
    const int tid  = threadIdx.x;
    const int lane = tid & 63;
    const int wm   = (tid >> 7) & 1;
    const int wn   = (tid >> 6) & 1;
    const int mt = blockIdx.y;
    int k0 = blockIdx.x * klen;
    int k1 = (k0 + klen > K) ? K : k0 + klen;
    const int bn0 = 0;
    const int bm0 = mt * 128;
    __shared__ u16 Als[128 * 64];
    __shared__ u16 Bls[128 * 64];
    fvec4 acc[4][4] = {};

    for (int kt = k0; kt < k1; kt += 64) {
#pragma unroll
        for (int i = 0; i < 4; ++i) {
            int idx = i * 256 + tid;
            int r  = idx >> 3;
            int kc = (idx & 7) << 3;
            int rl = bm0 + r; if (rl > Mloc - 1) rl = Mloc - 1;
            gld16(A + (size_t)rl * lda + kt + kc, &Als[idx * 8]);
            gld16(Bt + (size_t)(bn0 + r) * K + kt + kc, &Bls[idx * 8]);
        }
        __syncthreads();
#pragma unroll
        for (int kk = 0; kk < 2; ++kk) {
            int ko = kk * 32 + ((lane >> 4) << 3);
            bvec8 af[4], bfr[4];
#pragma unroll
            for (int m = 0; m < 4; ++m)
                af[m] = *(const bvec8*)&Als[(wm * 64 + m * 16 + (lane & 15)) * 64 + ko];
#pragma unroll
            for (int n = 0; n < 4; ++n)
                bfr[n] = *(const bvec8*)&Bls[(wn * 64 + n * 16 + (lane & 15)) * 64 + ko];
#pragma unroll
            for (int m = 0; m < 4; ++m)
#pragma unroll
                for (int n = 0; n < 4; ++n)
                    acc[m][n] = __builtin_amdgcn_mfma_f32_16x16x32_bf16(af[m], bfr[n], acc[m][n], 0, 0, 0);
        }
        __syncthreads();
    }

#pragma unroll
    for (int m = 0; m < 4; ++m) {
        int rbase = bm0 + wm * 64 + m * 16 + ((lane >> 4) << 2);
#pragma unroll
        for (int n = 0; n < 4; ++n) {
            int col = bn0 + wn * 64 + n * 16 + (lane & 15);
            if (col < N) {
#pragma unroll
                for (int q = 0; q < 4; ++q) {
                    int rl = rbase + q;
                    if (rl < Mloc) {
                        float* yp = (float*)Cp + (size_t)blockIdx.x * pstride;
                        yp[(size_t)(c_off + rl) * ldc + col] = acc[m][n][q];
                    }
                }
            }
        }
    }
}

// -------- final: sum 3 fc2 partials + bias, de-norm + transpose -> out(b,p,d) --------
__global__ __launch_bounds__(256) void final_denorm(const float* __restrict__ YP,
                                                    const float* __restrict__ fc2b,
                                                    const float* __restrict__ mean,
                                                    const float* __restrict__ stdv,
                                                    const float* __restrict__ rw,
                                                    const float* __restrict__ rb,
                                                    float* __restrict__ out) {
    const long long PART = (long long)BDTOT * PREDL;
    __shared__ float t[32][33];
    int d0 = blockIdx.x * 32, p0 = blockIdx.y * 32, b = blockIdx.z;
    for (int e = threadIdx.x; e < 1024; e += 256) {
        int di = e >> 5, pj = e & 31;
        int d = d0 + di, p = p0 + pj;
        if (d < DCH && p < PREDL) {
            size_t off = ((size_t)b * DCH + d) * PREDL + p;
            t[di][pj] = YP[off] + YP[off + PART] + YP[off + 2 * PART] + fc2b[p];
        } else t[di][pj] = 0.f;
    }
    __syncthreads();
    for (int e = threadIdx.x; e < 1024; e += 256) {
        int pi = e >> 5, dj = e & 31;
        int d = d0 + dj, p = p0 + pi;
        if (d < DCH && p < PREDL) {
            int bd = b * DCH + d;
            float v = (t[dj][pi] - rb[d]) / (rw[d] + 1e-10f) * stdv[bd] + mean[bd];
            out[((size_t)b * PREDL + p) * DCH + d] = v;
        }
    }
}

extern "C" void kernel_launch(void* const* d_in, const int* in_sizes, int n_in,
                              void* d_out, int out_size, void* d_ws, size_t ws_size,
                              hipStream_t stream) {
    const float* x      = (const float*)d_in[0];
    const float* window = (const float*)d_in[4];
    const float* rw     = (const float*)d_in[5];
    const float* rb     = (const float*)d_in[6];
    const float* l0wr = (const float*)d_in[7],  *l0wi = (const float*)d_in[8];
    const float* l0br = (const float*)d_in[9],  *l0bi = (const float*)d_in[10];
    const float* l1wr = (const float*)d_in[11], *l1wi = (const float*)d_in[12];
    const float* l1br = (const float*)d_in[13], *l1bi = (const float*)d_in[14];
    const float* l2wr = (const float*)d_in[15], *l2wi = (const float*)d_in[16];
    const float* l2br = (const float*)d_in[17], *l2bi = (const float*)d_in[18];
    const float* m0wr = (const float*)d_in[19], *m0wi = (const float*)d_in[20];
    const float* m0br = (const float*)d_in[21], *m0bi = (const float*)d_in[22];
    const float* m1wr = (const float*)d_in[23], *m1wi = (const float*)d_in[24];
    const float* m1br = (const float*)d_in[25], *m1bi = (const float*)d_in[26];
    const float* h0wr = (const float*)d_in[27], *h0wi = (const float*)d_in[28];
    const float* h0br = (const float*)d_in[29], *h0bi = (const float*)d_in[30];
    const float* fc1w = (const float*)d_in[31];
    const float* fc1b = (const float*)d_in[32];
    const float* fc2w = (const float*)d_in[33];
    const float* fc2b = (const float*)d_in[34];

    char* p = (char*)d_ws;
    auto alloc = [&](size_t n) { char* r = p; p += (n + 255) & ~(size_t)255; return r; };
    float* mean  = (float*)alloc(BDTOT * 4);
    float* rstd  = (float*)alloc(BDTOT * 4);
    float* stdv  = (float*)alloc(BDTOT * 4);
    float* bias1 = (float*)alloc(192 * 4);
    float* bias2 = (float*)alloc(128 * 4);
    float* biast = (float*)alloc(64 * 4);
    u16* A1t   = (u16*)alloc(256 * 64 * 2);
    u16* W1t   = (u16*)alloc(128 * 64 * 2);
    u16* B2t   = (u16*)alloc(128 * 192 * 2);
    u16* fc1wT = (u16*)alloc((size_t)2048 * 1088 * 2);
    u16* fc2wT = (u16*)alloc((size_t)128 * 2048 * 2);
    u16* xnT   = (u16*)alloc((size_t)BDTOT * 576 * 2);   // dead after spectral phase
    float* YP  = (float*)xnT;   // alias: 3 fc2 partials = 3*20544*96*4 == xnT bytes exactly
    u16* EMB   = (u16*)alloc((size_t)BDTOT * 1088 * 2);

    size_t fixed_end = (size_t)(p - (char*)d_ws);
    int CH = 16;
    const int chs[5] = {1, 2, 4, 8, 16};
    for (int ci = 0; ci < 5; ++ci) {
        int c = chs[ci];
        size_t hbuf = (size_t)(BDTOT / c) * 2048 * 2;
        if (fixed_end + hbuf <= ws_size) { CH = c; break; }
    }
    int bd_c = BDTOT / CH;
    u16* Hbuf = (u16*)p;

    hipFuncSetAttribute(reinterpret_cast<const void*>(&gemm256<1>),
                        hipFuncAttributeMaxDynamicSharedMemorySize, 131072);

    dim3 blk(256);
    stats_kernel<<<BDTOT / 64, blk, 0, stream>>>(x, mean, rstd, stdv);
    norm_transpose<<<dim3(6, 8, NB), blk, 0, stream>>>(x, mean, rstd, rw, rb, xnT);
    pad_zero<<<(BDTOT * 64 + 255) / 256, blk, 0, stream>>>(xnT);
    precompute_kernel<<<194, blk, 0, stream>>>(window,
        l0wr, l0wi, l0br, l0bi, l1wr, l1wi, l1br, l1bi, l2wr, l2wi, l2br, l2bi,
        m0wr, m0wi, m0br, m0bi, m1wr, m1wi, m1br, m1bi, h0wr, h0wi, h0br, h0bi,
        A1t, W1t, B2t, bias1, bias2, biast);
    wtrans<<<dim3(64, 34), blk, 0, stream>>>(fc1w, fc1wT, 1088, 2048, 2048);
    wtrans<<<dim3(4, 64),  blk, 0, stream>>>(fc2w, fc2wT, 2048, 96, 128);

    spectral_fused<<<MWTOT / 64, blk, 0, stream>>>(xnT, A1t, W1t, B2t, bias1, bias2, biast, EMB);

    const long long PART = (long long)BDTOT * PREDL;
    for (int c = 0; c < CH; ++c) {
        long long boff = (long long)c * bd_c;
        int gm = (bd_c + 255) / 256;
        int nwg = 8 * gm;
        gemm256<1><<<dim3(nwg), dim3(512), 131072, stream>>>(EMB, fc1wT, fc1b, Hbuf,
            bd_c, 1088, 2048, boff, nwg);
        gemm_bt_splitk<<<dim3(3, (bd_c + 127) / 128), blk, 0, stream>>>(Hbuf, fc2wT, YP,
            bd_c, 96, 2048, 2048, 96, boff, 704, PART);
    }
    final_denorm<<<dim3(11, 3, NB), blk, 0, stream>>>(YP, fc2b, mean, stdv, rw, rb, (float*)d_out);
}

// Round 4
// 321.279 us; speedup vs baseline: 2.0100x; 1.0817x over previous
//
#include <hip/hip_runtime.h>

typedef unsigned short u16;
typedef unsigned int   u32;
typedef __attribute__((ext_vector_type(4))) float  fvec4;
typedef __attribute__((ext_vector_type(8))) __bf16 bvec8;

#define NB    64
#define SEQL  512
#define DCH   321
#define BDTOT (NB * DCH)      /* 20544 */
#define NWIN  17
#define PREDL 96
#define MWTOT (BDTOT * NWIN)  /* 349248 */
#define KPAD  1152            /* 1088 padded to 18*64 */

__device__ __forceinline__ u16 f2bf(float f) {
    union { float f; u32 u; } v; v.f = f;
    u32 r = v.u + 0x7FFFu + ((v.u >> 16) & 1u);
    return (u16)(r >> 16);
}
__device__ __forceinline__ float lrelu(float v) { return v > 0.f ? v : 0.01f * v; }

__device__ __forceinline__ void gld16(const u16* g, u16* l) {
    __builtin_amdgcn_global_load_lds((const __attribute__((address_space(1))) void*)g,
                                     (__attribute__((address_space(3))) void*)l, 16, 0, 0);
}

// ---------------- stats: mean / rstd / std per (b,d) over SEQ ----------------
__global__ __launch_bounds__(256) void stats_kernel(const float* __restrict__ x,
                                                    float* __restrict__ mean,
                                                    float* __restrict__ rstd,
                                                    float* __restrict__ stdv) {
    __shared__ float ls[2][4][64];
    int i = threadIdx.x & 63;
    int j = threadIdx.x >> 6;
    int bd = blockIdx.x * 64 + i;
    int b = bd / DCH, d = bd - b * DCH;
    float s = 0.f, ss = 0.f;
    for (int t = j; t < SEQL; t += 4) {
        float v = x[((size_t)b * SEQL + t) * DCH + d];
        s += v; ss += v * v;
    }
    ls[0][j][i] = s; ls[1][j][i] = ss;
    __syncthreads();
    if (j == 0) {
        s  = ls[0][0][i] + ls[0][1][i] + ls[0][2][i] + ls[0][3][i];
        ss = ls[1][0][i] + ls[1][1][i] + ls[1][2][i] + ls[1][3][i];
        float m   = s * (1.f / SEQL);
        float var = ss * (1.f / SEQL) - m * m;
        float st  = sqrtf(var + 1e-5f);
        mean[bd] = m; rstd[bd] = 1.f / st; stdv[bd] = st;
    }
}

// -------- normalize + transpose: x(B,SEQ,D) -> xnT(B*D, 576) bf16, +32 pad --------
__global__ __launch_bounds__(256) void norm_transpose(const float* __restrict__ x,
                                                      const float* __restrict__ mean,
                                                      const float* __restrict__ rstd,
                                                      const float* __restrict__ rw,
                                                      const float* __restrict__ rb,
                                                      u16* __restrict__ xnT) {
    __shared__ float tile[64][65];
    int d0 = blockIdx.x * 64, s0 = blockIdx.y * 64, b = blockIdx.z;
    for (int e = threadIdx.x; e < 4096; e += 256) {
        int sr = e >> 6, dc = e & 63;
        int d = d0 + dc;
        tile[sr][dc] = (d < DCH) ? x[((size_t)b * SEQL + s0 + sr) * DCH + d] : 0.f;
    }
    __syncthreads();
    for (int e = threadIdx.x; e < 4096; e += 256) {
        int dr = e >> 6, sc = e & 63;
        int d = d0 + dr;
        if (d < DCH) {
            int bd = b * DCH + d;
            float v = (tile[sc][dr] - mean[bd]) * rstd[bd] * rw[d] + rb[d];
            xnT[(size_t)bd * 576 + 32 + s0 + sc] = f2bf(v);
        }
    }
}

__global__ __launch_bounds__(256) void pad_zero(u16* __restrict__ xnT) {
    int idx = blockIdx.x * 256 + threadIdx.x;
    if (idx < BDTOT * 64) {
        int bd = idx >> 6, q = idx & 63;
        int off = q < 32 ? q : 512 + q;   // [0,32) front, [544,576) back
        xnT[(size_t)bd * 576 + off] = 0;
    }
}

// zero EMB K-pad cols [1088,1152)
__global__ __launch_bounds__(256) void pad_emb(u16* __restrict__ EMB) {
    int idx = blockIdx.x * 256 + threadIdx.x;
    if (idx < BDTOT * 8) {
        int bd = idx >> 3, o = (idx & 7) * 8;
        fvec4 z = {0.f, 0.f, 0.f, 0.f};
        *(fvec4*)&EMB[(size_t)bd * KPAD + 1088 + o] = z;
    }
}

// -------- fold matrices: window*DFT*band-MLP layers + irfft, all precomputed --------
__global__ __launch_bounds__(256) void precompute_kernel(
    const float* __restrict__ window,
    const float* __restrict__ l0wr, const float* __restrict__ l0wi,
    const float* __restrict__ l0br, const float* __restrict__ l0bi,
    const float* __restrict__ l1wr, const float* __restrict__ l1wi,
    const float* __restrict__ l1br, const float* __restrict__ l1bi,
    const float* __restrict__ l2wr, const float* __restrict__ l2wi,
    const float* __restrict__ l2br, const float* __restrict__ l2bi,
    const float* __restrict__ m0wr, const float* __restrict__ m0wi,
    const float* __restrict__ m0br, const float* __restrict__ m0bi,
    const float* __restrict__ m1wr, const float* __restrict__ m1wi,
    const float* __restrict__ m1br, const float* __restrict__ m1bi,
    const float* __restrict__ h0wr, const float* __restrict__ h0wi,
    const float* __restrict__ h0br, const float* __restrict__ h0bi,
    u16* __restrict__ A1t, u16* __restrict__ W1t, u16* __restrict__ B2t,
    float* __restrict__ bias1, float* __restrict__ bias2, float* __restrict__ biast)
{
    int idx = blockIdx.x * 256 + threadIdx.x;
    float nrm = 0.f;
    for (int i = 0; i < 64; ++i) nrm += window[i] * window[i];
    float inv = 1.0f / sqrtf(nrm);
    const float STEP = 6.283185307179586f / 64.f;
    auto Cc = [&](int n, int k) { return  window[n] * inv * cosf(STEP * (float)((k * n) & 63)); };
    auto Ss = [&](int n, int k) { return -window[n] * inv * sinf(STEP * (float)((k * n) & 63)); };
    auto aRe = [&](int k, int n) {
        float sc = (k == 0 || k == 32) ? (1.f / 64.f) : (2.f / 64.f);
        return sc * cosf(STEP * (float)((k * n) & 63));
    };
    auto aIm = [&](int k, int n) {
        if (k == 0 || k == 32) return 0.f;            // numpy irfft ignores Im of bin0/Nyquist
        return -(2.f / 64.f) * sinf(STEP * (float)((k * n) & 63));
    };
    if (idx < 16384) {                                 // A1t [256 rows(pad)][64]
        int j = idx >> 6, n = idx & 63;
        float v = 0.f;
        if (j < 18)                    { for (int k = 0; k < 9;  ++k) v += Cc(n,k)   *l0wr[k*18+j]      - Ss(n,k)   *l0wi[k*18+j]; }
        else if (j < 36)               { int jj=j-18; for (int k = 0; k < 9;  ++k) v += Cc(n,k)   *l0wi[k*18+jj] + Ss(n,k)   *l0wr[k*18+jj]; }
        else if (j >= 64  && j < 90)   { int jj=j-64; for (int k = 0; k < 13; ++k) v += Cc(n,9+k) *m0wr[k*26+jj] - Ss(n,9+k) *m0wi[k*26+jj]; }
        else if (j >= 90  && j < 116)  { int jj=j-90; for (int k = 0; k < 13; ++k) v += Cc(n,9+k) *m0wi[k*26+jj] + Ss(n,9+k) *m0wr[k*26+jj]; }
        else if (j >= 128 && j < 139)  { int jj=j-128;for (int k = 0; k < 11; ++k) v += Cc(n,22+k)*h0wr[k*11+jj] - Ss(n,22+k)*h0wi[k*11+jj]; }
        else if (j >= 139 && j < 150)  { int jj=j-139;for (int k = 0; k < 11; ++k) v += Cc(n,22+k)*h0wi[k*11+jj] + Ss(n,22+k)*h0wr[k*11+jj]; }
        A1t[idx] = f2bf(v);
    } else if (idx < 24576) {                          // W1t [128(pad)][64]: low1 as real 36x36
        int t = idx - 16384; int j = t >> 6, k = t & 63;
        float v = 0.f;
        if (j < 18)      { if (k < 18) v = l1wr[k*18+j];        else if (k < 36) v = -l1wi[(k-18)*18+j]; }
        else if (j < 36) { int jj=j-18; if (k < 18) v = l1wi[k*18+jj]; else if (k < 36) v =  l1wr[(k-18)*18+jj]; }
        W1t[t] = f2bf(v);
    } else if (idx < 49152) {                          // B2t [128(pad)][192]: last layers + irfft
        int t = idx - 24576; int n = t / 192, c = t - n * 192;
        float v = 0.f;
        if (n < 64) {
            if (c < 18)                  { for (int m = 0; m < 9;  ++m) v +=  l2wr[c*9+m]     *aRe(m,n)   + l2wi[c*9+m]     *aIm(m,n); }
            else if (c < 36)             { int cc=c-18; for (int m = 0; m < 9;  ++m) v += -l2wi[cc*9+m]   *aRe(m,n)   + l2wr[cc*9+m]   *aIm(m,n); }
            else if (c >= 64 && c < 90)  { int cc=c-64; for (int m = 0; m < 13; ++m) v +=  m1wr[cc*13+m]  *aRe(9+m,n) + m1wi[cc*13+m]  *aIm(9+m,n); }
            else if (c >= 90 && c < 116) { int cc=c-90; for (int m = 0; m < 13; ++m) v += -m1wi[cc*13+m]  *aRe(9+m,n) + m1wr[cc*13+m]  *aIm(9+m,n); }
            else if (c >= 128 && c < 139){ v = aRe(22 + (c-128), n); }
            else if (c >= 139 && c < 150){ v = aIm(22 + (c-139), n); }
        }
        B2t[t] = f2bf(v);
    } else if (idx < 49344) {                          // bias1[192]
        int c = idx - 49152;
        float v = 0.f;
        if (c < 18) v = l0br[c];
        else if (c < 36) v = l0bi[c-18];
        else if (c >= 64 && c < 90) v = m0br[c-64];
        else if (c >= 90 && c < 116) v = m0bi[c-90];
        bias1[c] = v;
    } else if (idx < 49472) {                          // bias2[128]
        int c = idx - 49344;
        float v = 0.f;
        if (c < 18) v = l1br[c]; else if (c < 36) v = l1bi[c-18];
        bias2[c] = v;
    } else if (idx < 49536) {                          // biast[64]: all final biases thru irfft
        int n = idx - 49472;
        float v = 0.f;
        for (int k = 0; k <= 32; ++k) {
            float br = (k < 9) ? l2br[k] : (k < 22 ? m1br[k-9] : h0br[k-22]);
            float bi = (k < 9) ? l2bi[k] : (k < 22 ? m1bi[k-9] : h0bi[k-22]);
            v += aRe(k, n) * br + aIm(k, n) * bi;
        }
        biast[n] = v;
    }
}

// ---- transpose fp32 W[R][C] -> bf16 Wt[Cpad][ldw], rows rg in [R,ldw) zero-filled ----
__global__ __launch_bounds__(256) void wtrans(const float* __restrict__ W, u16* __restrict__ Wt,
                                              int R, int C, int Cpad, int ldw) {
    __shared__ float t[32][33];
    int c0 = blockIdx.x * 32, r0 = blockIdx.y * 32;
    for (int e = threadIdx.x; e < 1024; e += 256) {
        int rr = e >> 5, cc = e & 31;
        int rg = r0 + rr, cg = c0 + cc;
        t[rr][cc] = (rg < R && cg < C) ? W[(size_t)rg * C + cg] : 0.f;
    }
    __syncthreads();
    for (int e = threadIdx.x; e < 1024; e += 256) {
        int cr = e >> 5, rc = e & 31;
        int cg = c0 + cr, rg = r0 + rc;
        if (cg < Cpad && rg < ldw) Wt[(size_t)cg * ldw + rg] = f2bf(t[rc][cr]);
    }
}

// -------- fused spectral: windows -> stage1(192) -> stage2(low) -> stage3+irfft -> EMB --------
__global__ __launch_bounds__(256) void spectral_fused(
    const u16* __restrict__ xnT, const u16* __restrict__ A1t,
    const u16* __restrict__ W1t, const u16* __restrict__ B2t,
    const float* __restrict__ bias1, const float* __restrict__ bias2,
    const float* __restrict__ biast, u16* __restrict__ EMB)
{
    __shared__ u16 XB[64 * 72];     // 9 KB, window rows (stride 72: conflict-free)
    __shared__ u16 ACT[64 * 208];   // 26 KB, stage outputs (stride 208: ~4-way)
    const int tid  = threadIdx.x;
    const int lane = tid & 63;
    const int wn   = tid >> 6;            // 0..3
    const int r0   = blockIdx.x * 64;     // global window-row base (grid divides exactly)

    {   // stage window rows -> XB
        int rr = tid >> 2;
        int cc = (tid & 3) * 16;
        u32 gr = (u32)(r0 + rr);
        u32 bd = gr / 17u, nw = gr - bd * 17u;
        const u16* src = xnT + (size_t)bd * 576 + nw * 32 + cc;
        *(bvec8*)&XB[rr * 72 + cc]     = *(const bvec8*)(src);
        *(bvec8*)&XB[rr * 72 + cc + 8] = *(const bvec8*)(src + 8);
    }
    __syncthreads();

    // ---- stage 1: ACT[64x192] = window @ A1^T, bias1, lrelu on cols<128 ----
    fvec4 acc1[4][3] = {};
#pragma unroll
    for (int kk = 0; kk < 2; ++kk) {
        int ko = kk * 32 + ((lane >> 4) << 3);
        bvec8 af[4], bf[3];
#pragma unroll
        for (int m = 0; m < 4; ++m)
            af[m] = *(const bvec8*)&XB[(m * 16 + (lane & 15)) * 72 + ko];
#pragma unroll
        for (int n = 0; n < 3; ++n)
            bf[n] = *(const bvec8*)(A1t + (size_t)(wn * 48 + n * 16 + (lane & 15)) * 64 + ko);
#pragma unroll
        for (int m = 0; m < 4; ++m)
#pragma unroll
            for (int n = 0; n < 3; ++n)
                acc1[m][n] = __builtin_amdgcn_mfma_f32_16x16x32_bf16(af[m], bf[n], acc1[m][n], 0, 0, 0);
    }
#pragma unroll
    for (int n = 0; n < 3; ++n) {
        int col = wn * 48 + n * 16 + (lane & 15);
        float bs = bias1[col];
#pragma unroll
        for (int m = 0; m < 4; ++m)
#pragma unroll
            for (int q = 0; q < 4; ++q) {
                int row = m * 16 + ((lane >> 4) << 2) + q;
                float v = acc1[m][n][q] + bs;
                if (col < 128) v = lrelu(v);
                ACT[row * 208 + col] = f2bf(v);
            }
    }
    __syncthreads();

    // ---- stage 2: low1 over K = cols 0..63, output cols 0..63 (in place) ----
    fvec4 acc2[4] = {};
#pragma unroll
    for (int kk = 0; kk < 2; ++kk) {
        int ko = kk * 32 + ((lane >> 4) << 3);
        bvec8 bf = *(const bvec8*)(W1t + (size_t)(wn * 16 + (lane & 15)) * 64 + ko);
#pragma unroll
        for (int m = 0; m < 4; ++m) {
            bvec8 af = *(const bvec8*)&ACT[(m * 16 + (lane & 15)) * 208 + ko];
            acc2[m] = __builtin_amdgcn_mfma_f32_16x16x32_bf16(af, bf, acc2[m], 0, 0, 0);
        }
    }
    __syncthreads();   // all stage-2 reads done before overwrite
    {
        int col = wn * 16 + (lane & 15);
        float bs = bias2[col];
#pragma unroll
        for (int m = 0; m < 4; ++m)
#pragma unroll
            for (int q = 0; q < 4; ++q) {
                int row = m * 16 + ((lane >> 4) << 2) + q;
                ACT[row * 208 + col] = f2bf(lrelu(acc2[m][q] + bs));
            }
    }
    __syncthreads();

    // ---- stage 3: EMB[64x64] = ACT[64x192] @ B2^T + biast ----
    fvec4 acc3[4] = {};
#pragma unroll
    for (int kk = 0; kk < 6; ++kk) {
        int ko = kk * 32 + ((lane >> 4) << 3);
        bvec8 bf = *(const bvec8*)(B2t + (size_t)(wn * 16 + (lane & 15)) * 192 + ko);
#pragma unroll
        for (int m = 0; m < 4; ++m) {
            bvec8 af = *(const bvec8*)&ACT[(m * 16 + (lane & 15)) * 208 + ko];
            acc3[m] = __builtin_amdgcn_mfma_f32_16x16x32_bf16(af, bf, acc3[m], 0, 0, 0);
        }
    }
    {
        int col = wn * 16 + (lane & 15);
        float bs = biast[col];
#pragma unroll
        for (int m = 0; m < 4; ++m)
#pragma unroll
            for (int q = 0; q < 4; ++q) {
                int row = m * 16 + ((lane >> 4) << 2) + q;
                int wr = r0 + row;
                int bd2 = wr / 17, nw2 = wr - bd2 * 17;
                EMB[(size_t)bd2 * KPAD + nw2 * 64 + col] = f2bf(acc3[m][q] + bs);
            }
    }
}

// ======== fc1: 256x256 / BK=64 phase-split GEMM (T2+T3+T4+T5 stack) ========
// 4 phases per K-tile; per phase: {ds_read quadrant | stage 1/4 of next tile}
// -> barrier -> setprio(1) 16xMFMA setprio(0) -> [p3: vmcnt(0)] -> barrier.
// T2: chunk-XOR swizzle, applied on the pre-swizzled GLOBAL source (linear
// global_load_lds dest) and on the ds_read address (rule #21 involution).
// Prefetch distance = 1 full K-tile (loads issued one iteration ahead).
template <int SWZ>
__global__ __launch_bounds__(512, 2) void gemm256_8ph(
    const u16* __restrict__ A, const u16* __restrict__ Bt,
    const float* __restrict__ bias, u16* __restrict__ C,
    int Mloc, int K, int ldc, long long a_off, int nwg)
{
    extern __shared__ u16 lds[];            // [2][A 16384 u16 | B 16384 u16]
    const int tid  = threadIdx.x;
    const int lane = tid & 63;
    const int l15  = lane & 15;
    const int hi   = lane >> 4;
    const int wid  = tid >> 6;
    const int wm   = wid >> 2;              // 0..1
    const int wn   = wid & 3;               // 0..3
    int wg;
    if (SWZ) {
        int bid = blockIdx.x;
        int q = nwg >> 3, r = nwg & 7, xcd = bid & 7, off = bid >> 3;
        wg = (xcd < r) ? (xcd * (q + 1) + off) : (r * (q + 1) + (xcd - r) * q + off);
    } else wg = blockIdx.x;
    const int mt = wg >> 3;                 // N=2048 -> 8 n-tiles, nt-fastest
    const int nt = wg & 7;
    const int bm0 = mt * 256, bn0 = nt * 256;

    // per-thread global source bases for the 4 stage units x 2 loads.
    // unit u: mat = u>>1 (0=A,1=B), half = u&1. LDS dest is linear (idx*16B);
    // source column chunk is (chunk ^ (row&7)) -> inverse swizzle at the source.
    const u16* sbase[4][2];
#pragma unroll
    for (int u = 0; u < 4; ++u) {
        const int mat = u >> 1, half = u & 1;
#pragma unroll
        for (int j = 0; j < 2; ++j) {
            int idx = j * 512 + tid;
            int row = half * 128 + (idx >> 3);
            int kc = ((idx & 7) ^ (row & 7)) << 3;
            if (mat == 0) {
                int rl = bm0 + row; if (rl > Mloc - 1) rl = Mloc - 1;
                sbase[u][j] = A + (size_t)(a_off + rl) * K + kc;
            } else {
                sbase[u][j] = Bt + (size_t)(bn0 + row) * K + kc;
            }
        }
    }
    auto stage_unit = [&](int bufb, int tg, int u) {
        const int mat = u >> 1, half = u & 1;
        u16* dstb = lds + bufb * 32768 + mat * 16384 + half * 8192;
#pragma unroll
        for (int j = 0; j < 2; ++j) {
            int idx = j * 512 + tid;
            gld16(sbase[u][j] + ((size_t)tg << 6), dstb + idx * 8);
        }
    };

    fvec4 acc[8][4] = {};
    const int NT = K >> 6;                  // 18

    // prologue: stage tile 0 into buf0, drain, barrier
#pragma unroll
    for (int u = 0; u < 4; ++u) stage_unit(0, 0, u);
    asm volatile("s_waitcnt vmcnt(0)" ::: "memory");
    __builtin_amdgcn_sched_barrier(0);
    __builtin_amdgcn_s_barrier();
    __builtin_amdgcn_sched_barrier(0);

    for (int t = 0; t < NT; ++t) {
        const int cur = t & 1;
        const u16* Ab = lds + cur * 32768;
        const u16* Bb = Ab + 16384;
        const bool notlast = (t < NT - 1);
        bvec8 bfr[4];
#pragma unroll
        for (int p = 0; p < 4; ++p) {
            const int kk = p >> 1, mh = p & 1;
            bvec8 af[4];
            if (mh == 0) {
#pragma unroll
                for (int n = 0; n < 4; ++n) {
                    int r = wn * 64 + n * 16 + l15;
                    int bc = (kk * 4 + hi) ^ (l15 & 7);
                    bfr[n] = *(const bvec8*)&Bb[r * 64 + bc * 8];
                }
            }
#pragma unroll
            for (int mm = 0; mm < 4; ++mm) {
                int r = wm * 128 + (mh * 4 + mm) * 16 + l15;
                int bc = (kk * 4 + hi) ^ (l15 & 7);
                af[mm] = *(const bvec8*)&Ab[r * 64 + bc * 8];
            }
            if (notlast) stage_unit(cur ^ 1, t + 1, p);
            __builtin_amdgcn_sched_barrier(0);
            __builtin_amdgcn_s_barrier();
            __builtin_amdgcn_sched_barrier(0);
            __builtin_amdgcn_s_setprio(1);
#pragma unroll
            for (int mm = 0; mm < 4; ++mm)
#pragma unroll
                for (int n = 0; n < 4; ++n)
                    acc[mh * 4 + mm][n] = __builtin_amdgcn_mfma_f32_16x16x32_bf16(
                        af[mm], bfr[n], acc[mh * 4 + mm][n], 0, 0, 0);
            __builtin_amdgcn_s_setprio(0);
            if (p == 3) {
                // drain next-tile stage (issued phases 0..3) before buffer swap
                asm volatile("s_waitcnt vmcnt(0)" ::: "memory");
            }
            __builtin_amdgcn_sched_barrier(0);
            __builtin_amdgcn_s_barrier();
            __builtin_amdgcn_sched_barrier(0);
        }
    }

    // epilogue: bias + lrelu -> bf16
#pragma unroll
    for (int m = 0; m < 8; ++m) {
        int rl0 = bm0 + wm * 128 + m * 16 + ((lane >> 4) << 2);
#pragma unroll
        for (int n = 0; n < 4; ++n) {
            int col = bn0 + wn * 64 + n * 16 + l15;
            float bs = bias[col];
#pragma unroll
            for (int q = 0; q < 4; ++q) {
                int rl = rl0 + q;
                if (rl < Mloc)
                    C[(size_t)rl * (size_t)ldc + col] = f2bf(lrelu(acc[m][n][q] + bs));
            }
        }
    }
}

// -------- 128x128 / BK=64 GEMM, fc2 split-K partial (fp32 out, no bias) --------
__global__ __launch_bounds__(256) void gemm_bt_splitk(
    const u16* __restrict__ A, const u16* __restrict__ Bt,
    void* __restrict__ Cp, int Mloc, int N, int K, int lda, int ldc,
    long long c_off, int klen, long long pstride)
{
    const int tid  = threadIdx.x;
    const int lane = tid & 63;
    const int wm   = (tid >> 7) & 1;
    const int wn   = (tid >> 6) & 1;
    const int mt = blockIdx.y;
    int k0 = blockIdx.x * klen;
    int k1 = (k0 + klen > K) ? K : k0 + klen;
    const int bn0 = 0;
    const int bm0 = mt * 128;
    __shared__ u16 Als[128 * 64];
    __shared__ u16 Bls[128 * 64];
    fvec4 acc[4][4] = {};

    for (int kt = k0; kt < k1; kt += 64) {
#pragma unroll
        for (int i = 0; i < 4; ++i) {
            int idx = i * 256 + tid;
            int r  = idx >> 3;
            int kc = (idx & 7) << 3;
            int rl = bm0 + r; if (rl > Mloc - 1) rl = Mloc - 1;
            gld16(A + (size_t)rl * lda + kt + kc, &Als[idx * 8]);
            gld16(Bt + (size_t)(bn0 + r) * K + kt + kc, &Bls[idx * 8]);
        }
        __syncthreads();
#pragma unroll
        for (int kk = 0; kk < 2; ++kk) {
            int ko = kk * 32 + ((lane >> 4) << 3);
            bvec8 af[4], bfr[4];
#pragma unroll
            for (int m = 0; m < 4; ++m)
                af[m] = *(const bvec8*)&Als[(wm * 64 + m * 16 + (lane & 15)) * 64 + ko];
#pragma unroll
            for (int n = 0; n < 4; ++n)
                bfr[n] = *(const bvec8*)&Bls[(wn * 64 + n * 16 + (lane & 15)) * 64 + ko];
#pragma unroll
            for (int m = 0; m < 4; ++m)
#pragma unroll
                for (int n = 0; n < 4; ++n)
                    acc[m][n] = __builtin_amdgcn_mfma_f32_16x16x32_bf16(af[m], bfr[n], acc[m][n], 0, 0, 0);
        }
        __syncthreads();
    }

#pragma unroll
    for (int m = 0; m < 4; ++m) {
        int rbase = bm0 + wm * 64 + m * 16 + ((lane >> 4) << 2);
#pragma unroll
        for (int n = 0; n < 4; ++n) {
            int col = bn0 + wn * 64 + n * 16 + (lane & 15);
            if (col < N) {
#pragma unroll
                for (int q = 0; q < 4; ++q) {
                    int rl = rbase + q;
                    if (rl < Mloc) {
                        float* yp = (float*)Cp + (size_t)blockIdx.x * pstride;
                        yp[(size_t)(c_off + rl) * ldc + col] = acc[m][n][q];
                    }
                }
            }
        }
    }
}

// -------- final: sum 3 fc2 partials + bias, de-norm + transpose -> out(b,p,d) --------
__global__ __launch_bounds__(256) void final_denorm(const float* __restrict__ YP,
                                                    const float* __restrict__ fc2b,
                                                    const float* __restrict__ mean,
                                                    const float* __restrict__ stdv,
                                                    const float* __restrict__ rw,
                                                    const float* __restrict__ rb,
                                                    float* __restrict__ out) {
    const long long PART = (long long)BDTOT * PREDL;
    __shared__ float t[32][33];
    int d0 = blockIdx.x * 32, p0 = blockIdx.y * 32, b = blockIdx.z;
    for (int e = threadIdx.x; e < 1024; e += 256) {
        int di = e >> 5, pj = e & 31;
        int d = d0 + di, p = p0 + pj;
        if (d < DCH && p < PREDL) {
            size_t off = ((size_t)b * DCH + d) * PREDL + p;
            t[di][pj] = YP[off] + YP[off + PART] + YP[off + 2 * PART] + fc2b[p];
        } else t[di][pj] = 0.f;
    }
    __syncthreads();
    for (int e = threadIdx.x; e < 1024; e += 256) {
        int pi = e >> 5, dj = e & 31;
        int d = d0 + dj, p = p0 + pi;
        if (d < DCH && p < PREDL) {
            int bd = b * DCH + d;
            float v = (t[dj][pi] - rb[d]) / (rw[d] + 1e-10f) * stdv[bd] + mean[bd];
            out[((size_t)b * PREDL + p) * DCH + d] = v;
        }
    }
}

extern "C" void kernel_launch(void* const* d_in, const int* in_sizes, int n_in,
                              void* d_out, int out_size, void* d_ws, size_t ws_size,
                              hipStream_t stream) {
    const float* x      = (const float*)d_in[0];
    const float* window = (const float*)d_in[4];
    const float* rw     = (const float*)d_in[5];
    const float* rb     = (const float*)d_in[6];
    const float* l0wr = (const float*)d_in[7],  *l0wi = (const float*)d_in[8];
    const float* l0br = (const float*)d_in[9],  *l0bi = (const float*)d_in[10];
    const float* l1wr = (const float*)d_in[11], *l1wi = (const float*)d_in[12];
    const float* l1br = (const float*)d_in[13], *l1bi = (const float*)d_in[14];
    const float* l2wr = (const float*)d_in[15], *l2wi = (const float*)d_in[16];
    const float* l2br = (const float*)d_in[17], *l2bi = (const float*)d_in[18];
    const float* m0wr = (const float*)d_in[19], *m0wi = (const float*)d_in[20];
    const float* m0br = (const float*)d_in[21], *m0bi = (const float*)d_in[22];
    const float* m1wr = (const float*)d_in[23], *m1wi = (const float*)d_in[24];
    const float* m1br = (const float*)d_in[25], *m1bi = (const float*)d_in[26];
    const float* h0wr = (const float*)d_in[27], *h0wi = (const float*)d_in[28];
    const float* h0br = (const float*)d_in[29], *h0bi = (const float*)d_in[30];
    const float* fc1w = (const float*)d_in[31];
    const float* fc1b = (const float*)d_in[32];
    const float* fc2w = (const float*)d_in[33];
    const float* fc2b = (const float*)d_in[34];

    char* p = (char*)d_ws;
    auto alloc = [&](size_t n) { char* r = p; p += (n + 255) & ~(size_t)255; return r; };
    float* mean  = (float*)alloc(BDTOT * 4);
    float* rstd  = (float*)alloc(BDTOT * 4);
    float* stdv  = (float*)alloc(BDTOT * 4);
    float* bias1 = (float*)alloc(192 * 4);
    float* bias2 = (float*)alloc(128 * 4);
    float* biast = (float*)alloc(64 * 4);
    u16* A1t   = (u16*)alloc(256 * 64 * 2);
    u16* W1t   = (u16*)alloc(128 * 64 * 2);
    u16* B2t   = (u16*)alloc(128 * 192 * 2);
    u16* fc1wT = (u16*)alloc((size_t)2048 * KPAD * 2);
    u16* fc2wT = (u16*)alloc((size_t)128 * 2048 * 2);
    u16* xnT   = (u16*)alloc((size_t)BDTOT * 576 * 2);   // dead after spectral phase
    float* YP  = (float*)xnT;   // alias: 3 fc2 partials = 3*20544*96*4 == xnT bytes exactly
    u16* EMB   = (u16*)alloc((size_t)BDTOT * KPAD * 2);

    size_t fixed_end = (size_t)(p - (char*)d_ws);
    int CH = 16;
    const int chs[5] = {1, 2, 4, 8, 16};
    for (int ci = 0; ci < 5; ++ci) {
        int c = chs[ci];
        size_t hbuf = (size_t)(BDTOT / c) * 2048 * 2;
        if (fixed_end + hbuf <= ws_size) { CH = c; break; }
    }
    int bd_c = BDTOT / CH;
    u16* Hbuf = (u16*)p;

    hipFuncSetAttribute(reinterpret_cast<const void*>(&gemm256_8ph<1>),
                        hipFuncAttributeMaxDynamicSharedMemorySize, 131072);

    dim3 blk(256);
    stats_kernel<<<BDTOT / 64, blk, 0, stream>>>(x, mean, rstd, stdv);
    norm_transpose<<<dim3(6, 8, NB), blk, 0, stream>>>(x, mean, rstd, rw, rb, xnT);
    pad_zero<<<(BDTOT * 64 + 255) / 256, blk, 0, stream>>>(xnT);
    precompute_kernel<<<194, blk, 0, stream>>>(window,
        l0wr, l0wi, l0br, l0bi, l1wr, l1wi, l1br, l1bi, l2wr, l2wi, l2br, l2bi,
        m0wr, m0wi, m0br, m0bi, m1wr, m1wi, m1br, m1bi, h0wr, h0wi, h0br, h0bi,
        A1t, W1t, B2t, bias1, bias2, biast);
    wtrans<<<dim3(64, 36), blk, 0, stream>>>(fc1w, fc1wT, 1088, 2048, 2048, KPAD);
    wtrans<<<dim3(4, 64),  blk, 0, stream>>>(fc2w, fc2wT, 2048, 96, 128, 2048);

    spectral_fused<<<MWTOT / 64, blk, 0, stream>>>(xnT, A1t, W1t, B2t, bias1, bias2, biast, EMB);
    pad_emb<<<(BDTOT * 8 + 255) / 256, blk, 0, stream>>>(EMB);

    const long long PART = (long long)BDTOT * PREDL;
    for (int c = 0; c < CH; ++c) {
        long long boff = (long long)c * bd_c;
        int gm = (bd_c + 255) / 256;
        int nwg = 8 * gm;
        gemm256_8ph<1><<<dim3(nwg), dim3(512), 131072, stream>>>(EMB, fc1wT, fc1b, Hbuf,
            bd_c, KPAD, 2048, boff, nwg);
        gemm_bt_splitk<<<dim3(3, (bd_c + 127) / 128), blk, 0, stream>>>(Hbuf, fc2wT, YP,
            bd_c, 96, 2048, 2048, 96, boff, 704, PART);
    }
    final_denorm<<<dim3(11, 3, NB), blk, 0, stream>>>(YP, fc2b, mean, stdv, rw, rb, (float*)d_out);
}